// Round 1
// baseline (1228.849 us; speedup 1.0000x reference)
//
#include <hip/hip_runtime.h>
#include <hip/hip_bf16.h>
#include <math.h>

// ---------------- CSR build ----------------

__global__ void k_hist(int* __restrict__ deg, const int* __restrict__ dst, int E) {
    int i = blockIdx.x * blockDim.x + threadIdx.x;
    if (i < E) atomicAdd(&deg[dst[i]], 1);
}

// single-block exclusive scan: deg[0..n) -> ptr[0..n], cur[0..n)
__global__ void k_scan(const int* __restrict__ deg, int* __restrict__ ptrArr,
                       int* __restrict__ cur, int n) {
    __shared__ int sh[1024];
    int t = threadIdx.x;
    int chunk = (n + 1023) / 1024;
    int lo = t * chunk;
    int hi = lo + chunk; if (hi > n) hi = n; if (lo > n) lo = n;
    int s = 0;
    for (int i = lo; i < hi; i++) s += deg[i];
    sh[t] = s;
    __syncthreads();
    for (int off = 1; off < 1024; off <<= 1) {
        int v = sh[t];
        int u = (t >= off) ? sh[t - off] : 0;
        __syncthreads();
        sh[t] = v + u;
        __syncthreads();
    }
    int run = (t == 0) ? 0 : sh[t - 1];
    for (int i = lo; i < hi; i++) {
        ptrArr[i] = run; cur[i] = run; run += deg[i];
    }
    if (t == 1023) ptrArr[n] = sh[1023];
}

__global__ void k_scatter(int* __restrict__ csr, int* __restrict__ cur,
                          const int* __restrict__ src, const int* __restrict__ dst, int E) {
    int i = blockIdx.x * blockDim.x + threadIdx.x;
    if (i < E) {
        int pos = atomicAdd(&cur[dst[i]], 1);
        csr[pos] = src[i];
    }
}

// ---------------- weight prep ----------------
// V1[k][j], k<500, j<16: j in [0,4)=src head j, [4,8)=dst1 head j-4, [8,12)=dst21, [12,16)=0
__global__ void k_build_V1(const float* __restrict__ Ws, const float* __restrict__ Wd,
                           const float* __restrict__ Wd2, const float* __restrict__ as_,
                           const float* __restrict__ ad, const float* __restrict__ ad2,
                           float* __restrict__ V) {
    int t = blockIdx.x * blockDim.x + threadIdx.x;
    if (t >= 500 * 16) return;
    int k = t >> 4, j = t & 15;
    float s = 0.f;
    if (j < 12) {
        int h = j & 3;
        const float* W; const float* a;
        if (j < 4)      { W = Ws;  a = as_; }
        else if (j < 8) { W = Wd;  a = ad;  }
        else            { W = Wd2; a = ad2; }
        #pragma unroll 8
        for (int c = 0; c < 32; c++) s += W[k * 128 + h * 32 + c] * a[h * 32 + c];
    }
    V[k * 16 + j] = s;
}

// Wc2[k][j], k<256, j<48: j<40 = W_src2[k][j]; 40..42 = al-projection cols; 43..47 = 0
__global__ void k_build_W2(const float* __restrict__ Ws, const float* __restrict__ Wd,
                           const float* __restrict__ Wd2, const float* __restrict__ as_,
                           const float* __restrict__ ad, const float* __restrict__ ad2,
                           float* __restrict__ Wc) {
    int t = blockIdx.x * blockDim.x + threadIdx.x;
    if (t >= 256 * 48) return;
    int k = t / 48, j = t % 48;
    float v = 0.f;
    if (j < 40) v = Ws[k * 40 + j];
    else if (j == 40) { for (int c = 0; c < 40; c++) v += Ws [k * 40 + c] * as_[c]; }
    else if (j == 41) { for (int c = 0; c < 40; c++) v += Wd [k * 40 + c] * ad [c]; }
    else if (j == 42) { for (int c = 0; c < 40; c++) v += Wd2[k * 40 + c] * ad2[c]; }
    Wc[k * 48 + j] = v;
}

// ---------------- GEMM: C[M x BN] = A[M x K] @ B[K x BN] ----------------
// BM=64, BK=16, 256 threads; thread computes 4 rows x (BN/16) cols.
template <int BN>
__global__ __launch_bounds__(256) void k_gemm(const float* __restrict__ A, int lda,
                                              const float* __restrict__ B,
                                              float* __restrict__ C,
                                              int M, int K) {
    constexpr int BM = 64, BK = 16;
    constexpr int TC = BN / 16;
    __shared__ float As[BM][BK + 1];
    __shared__ float Bs[BK][BN];
    int tid = threadIdx.x;
    int rowBlk = blockIdx.x * BM;
    int tr = tid >> 4, tc = tid & 15;
    float acc[4][TC];
    #pragma unroll
    for (int i = 0; i < 4; i++)
        #pragma unroll
        for (int j = 0; j < TC; j++) acc[i][j] = 0.f;

    for (int k0 = 0; k0 < K; k0 += BK) {
        // A tile: thread loads 4 consecutive k's of one row
        int arow = tid >> 2, ac = (tid & 3) * 4;
        int gr = rowBlk + arow;
        #pragma unroll
        for (int i = 0; i < 4; i++) {
            int gk = k0 + ac + i;
            As[arow][ac + i] = (gr < M && gk < K) ? A[(long)gr * lda + gk] : 0.f;
        }
        // B tile: 16 threads per k-row, TC contiguous cols each
        int brow = tid >> 4, bc = (tid & 15) * TC;
        int gk = k0 + brow;
        #pragma unroll
        for (int j = 0; j < TC; j++)
            Bs[brow][bc + j] = (gk < K) ? B[(long)gk * BN + bc + j] : 0.f;
        __syncthreads();
        #pragma unroll
        for (int kk = 0; kk < BK; kk++) {
            float av[4], bv[TC];
            #pragma unroll
            for (int i = 0; i < 4; i++) av[i] = As[tr * 4 + i][kk];
            #pragma unroll
            for (int j = 0; j < TC; j++) bv[j] = Bs[kk][tc * TC + j];
            #pragma unroll
            for (int i = 0; i < 4; i++)
                #pragma unroll
                for (int j = 0; j < TC; j++) acc[i][j] += av[i] * bv[j];
        }
        __syncthreads();
    }
    #pragma unroll
    for (int i = 0; i < 4; i++) {
        int gr = rowBlk + tr * 4 + i;
        if (gr < M) {
            #pragma unroll
            for (int j = 0; j < TC; j++)
                C[(long)gr * BN + tc * TC + j] = acc[i][j];
        }
    }
}

// ---------------- propagate (gather per destination, one wave per node) -------
// out[d][idx] = elu?( (sum_e exp(lrelu(als[s]+ald[d]) - m) * xs[s][idx]) / (den + 1e-16) )
template <int H, int C, bool ELU>
__global__ __launch_bounds__(256) void k_prop(const int* __restrict__ ptr, const int* __restrict__ csr,
                                              const float* __restrict__ alsrc, int als,
                                              const float* __restrict__ aldst, int ald,
                                              const float* __restrict__ xs, int xss,
                                              float* __restrict__ out, int outs, int n) {
    int wid = (blockIdx.x * blockDim.x + threadIdx.x) >> 6;
    int lane = threadIdx.x & 63;
    if (wid >= n) return;
    int d = wid;
    int b = ptr[d], e = ptr[d + 1];

    float adv[H];
    #pragma unroll
    for (int h = 0; h < H; h++) adv[h] = aldst[(long)d * ald + h];

    // pass 1: segment max (lane-parallel over edges)
    float m[H];
    #pragma unroll
    for (int h = 0; h < H; h++) m[h] = -INFINITY;
    for (int p = b + lane; p < e; p += 64) {
        int s = csr[p];
        #pragma unroll
        for (int h = 0; h < H; h++) {
            float a = alsrc[(long)s * als + h] + adv[h];
            a = a > 0.f ? a : 0.2f * a;
            m[h] = fmaxf(m[h], a);
        }
    }
    #pragma unroll
    for (int h = 0; h < H; h++)
        for (int o = 32; o > 0; o >>= 1) m[h] = fmaxf(m[h], __shfl_xor(m[h], o, 64));

    // pass 2: denom (lane-parallel over edges)
    float den[H];
    #pragma unroll
    for (int h = 0; h < H; h++) den[h] = 0.f;
    for (int p = b + lane; p < e; p += 64) {
        int s = csr[p];
        #pragma unroll
        for (int h = 0; h < H; h++) {
            float a = alsrc[(long)s * als + h] + adv[h];
            a = a > 0.f ? a : 0.2f * a;
            den[h] += __expf(a - m[h]);
        }
    }
    #pragma unroll
    for (int h = 0; h < H; h++)
        for (int o = 32; o > 0; o >>= 1) den[h] += __shfl_xor(den[h], o, 64);

    // pass 3: accumulate messages (serial edges, lane-parallel channels)
    constexpr int HC = H * C;
    constexpr int PER = (HC + 63) / 64;
    float acc[PER];
    #pragma unroll
    for (int r = 0; r < PER; r++) acc[r] = 0.f;
    for (int p = b; p < e; ++p) {
        int s = csr[p];
        #pragma unroll
        for (int r = 0; r < PER; r++) {
            int idx = lane + 64 * r;
            if (idx < HC) {
                int h = idx / C;
                float a = alsrc[(long)s * als + h] + adv[h];
                a = a > 0.f ? a : 0.2f * a;
                float w = __expf(a - m[h]);
                acc[r] += w * xs[(long)s * xss + idx];
            }
        }
    }
    #pragma unroll
    for (int r = 0; r < PER; r++) {
        int idx = lane + 64 * r;
        if (idx < HC) {
            int h = idx / C;
            float v = acc[r] / (den[h] + 1e-16f);
            if (ELU) v = v > 0.f ? v : __expf(v) - 1.f;
            out[(long)d * outs + idx] = v;
        }
    }
}

// ---------------- log_softmax over 80 cols, one wave per row ----------------
__global__ __launch_bounds__(256) void k_lsm(const float* __restrict__ h2, float* __restrict__ out, int n) {
    int wid = (blockIdx.x * blockDim.x + threadIdx.x) >> 6;
    int lane = threadIdx.x & 63;
    if (wid >= n) return;
    const float* row = h2 + (long)wid * 80;
    float v0 = row[lane];                               // lanes 0..63 all < 80
    float v1 = (lane < 16) ? row[64 + lane] : -INFINITY;
    float m = fmaxf(v0, v1);
    for (int o = 32; o > 0; o >>= 1) m = fmaxf(m, __shfl_xor(m, o, 64));
    float s = __expf(v0 - m) + ((lane < 16) ? __expf(v1 - m) : 0.f);
    for (int o = 32; o > 0; o >>= 1) s += __shfl_xor(s, o, 64);
    float ls = m + logf(s);
    out[(long)wid * 80 + lane] = v0 - ls;
    if (lane < 16) out[(long)wid * 80 + 64 + lane] = v1 - ls;
}

// ---------------- launch ----------------

extern "C" void kernel_launch(void* const* d_in, const int* in_sizes, int n_in,
                              void* d_out, int out_size, void* d_ws, size_t ws_size,
                              hipStream_t stream) {
    const float* x       = (const float*)d_in[0];
    const int*   e1      = (const int*)d_in[1];
    const int*   e2      = (const int*)d_in[2];
    const float* W_src1  = (const float*)d_in[3];
    const float* W_dst1  = (const float*)d_in[4];
    const float* W_dst21 = (const float*)d_in[5];
    const float* a_src1  = (const float*)d_in[6];
    const float* a_dst1  = (const float*)d_in[7];
    const float* a_dst21 = (const float*)d_in[8];
    const float* W_src2  = (const float*)d_in[9];
    const float* W_dst2  = (const float*)d_in[10];
    const float* W_dst22 = (const float*)d_in[11];
    const float* a_src2  = (const float*)d_in[12];
    const float* a_dst2  = (const float*)d_in[13];
    const float* a_dst22 = (const float*)d_in[14];
    float* out = (float*)d_out;

    const int FIN = 500;
    int n  = in_sizes[0] / FIN;     // 50000
    int E1 = in_sizes[1] / 2;       // 300000
    int E2 = in_sizes[2] / 2;       // ~1.7M (runtime)
    const int* src1 = e1, *dst1 = e1 + E1;
    const int* src2 = e2, *dst2 = e2 + E2;

    // workspace layout
    char* w = (char*)d_ws;
    auto alloc = [&](size_t bytes) -> char* {
        char* p = w; w += (bytes + 255) & ~(size_t)255; return p;
    };
    float* xs1  = (float*)alloc((size_t)n * 128 * 4);  // layer1 src features (reused as h2)
    float* alb1 = (float*)alloc((size_t)n * 16 * 4);   // [als(4) | ald1(4) | ald21(4) | pad]
    float* hbuf = (float*)alloc((size_t)n * 256 * 4);  // elu(concat) hidden
    float* o2   = (float*)alloc((size_t)n * 48 * 4);   // [xs2(40) | als2 | ald2 | ald22 | pad]
    float* V1   = (float*)alloc(500 * 16 * 4);
    float* Wc2  = (float*)alloc(256 * 48 * 4);
    int* ptr1 = (int*)alloc((size_t)(n + 1) * 4);
    int* cur1 = (int*)alloc((size_t)n * 4);
    int* deg1 = (int*)alloc((size_t)n * 4);
    int* csr1 = (int*)alloc((size_t)E1 * 4);
    int* ptr2 = (int*)alloc((size_t)(n + 1) * 4);
    int* cur2 = (int*)alloc((size_t)n * 4);
    int* deg2 = (int*)alloc((size_t)n * 4);
    int* csr2 = (int*)alloc((size_t)E2 * 4);
    float* h2 = xs1;  // xs1 is dead before layer-2 propagate writes h2 (N*80 <= N*128)

    // CSR build
    hipMemsetAsync(deg1, 0, (size_t)n * 4, stream);
    hipMemsetAsync(deg2, 0, (size_t)n * 4, stream);
    k_hist<<<(E1 + 255) / 256, 256, 0, stream>>>(deg1, dst1, E1);
    k_hist<<<(E2 + 255) / 256, 256, 0, stream>>>(deg2, dst2, E2);
    k_scan<<<1, 1024, 0, stream>>>(deg1, ptr1, cur1, n);
    k_scan<<<1, 1024, 0, stream>>>(deg2, ptr2, cur2, n);
    k_scatter<<<(E1 + 255) / 256, 256, 0, stream>>>(csr1, cur1, src1, dst1, E1);
    k_scatter<<<(E2 + 255) / 256, 256, 0, stream>>>(csr2, cur2, src2, dst2, E2);

    // layer 1 linear
    k_build_V1<<<(500 * 16 + 255) / 256, 256, 0, stream>>>(W_src1, W_dst1, W_dst21,
                                                           a_src1, a_dst1, a_dst21, V1);
    k_gemm<128><<<(n + 63) / 64, 256, 0, stream>>>(x, FIN, W_src1, xs1, n, FIN);
    k_gemm<16><<<(n + 63) / 64, 256, 0, stream>>>(x, FIN, V1, alb1, n, FIN);

    // layer 1 propagate (+ fused ELU)
    int pblocks = (n + 3) / 4;
    k_prop<4, 32, true><<<pblocks, 256, 0, stream>>>(ptr1, csr1, alb1 + 0, 16, alb1 + 4, 16,
                                                     xs1, 128, hbuf + 0, 256, n);
    k_prop<4, 32, true><<<pblocks, 256, 0, stream>>>(ptr2, csr2, alb1 + 0, 16, alb1 + 8, 16,
                                                     xs1, 128, hbuf + 128, 256, n);

    // layer 2 linear
    k_build_W2<<<(256 * 48 + 255) / 256, 256, 0, stream>>>(W_src2, W_dst2, W_dst22,
                                                           a_src2, a_dst2, a_dst22, Wc2);
    k_gemm<48><<<(n + 63) / 64, 256, 0, stream>>>(hbuf, 256, Wc2, o2, n, 256);

    // layer 2 propagate
    k_prop<1, 40, false><<<pblocks, 256, 0, stream>>>(ptr1, csr1, o2 + 40, 48, o2 + 41, 48,
                                                      o2, 48, h2 + 0, 80, n);
    k_prop<1, 40, false><<<pblocks, 256, 0, stream>>>(ptr2, csr2, o2 + 40, 48, o2 + 42, 48,
                                                      o2, 48, h2 + 40, 80, n);

    // log_softmax
    k_lsm<<<pblocks, 256, 0, stream>>>(h2, out, n);
}

// Round 2
// 919.313 us; speedup vs baseline: 1.3367x; 1.3367x over previous
//
#include <hip/hip_runtime.h>
#include <hip/hip_bf16.h>
#include <math.h>

static __device__ __forceinline__ unsigned short f2bf(float f) {
    unsigned u = __float_as_uint(f);
    unsigned r = (u + 0x7fffu + ((u >> 16) & 1u)) >> 16;
    return (unsigned short)r;
}

// ---------------- CSR build ----------------

__global__ void k_hist(int* __restrict__ deg, const int* __restrict__ dst, int E) {
    int i = blockIdx.x * blockDim.x + threadIdx.x;
    if (i < E) atomicAdd(&deg[dst[i]], 1);
}

__global__ void k_scan(const int* __restrict__ deg, int* __restrict__ ptrArr,
                       int* __restrict__ cur, int n) {
    __shared__ int sh[1024];
    int t = threadIdx.x;
    int chunk = (n + 1023) / 1024;
    int lo = t * chunk;
    int hi = lo + chunk; if (hi > n) hi = n; if (lo > n) lo = n;
    int s = 0;
    for (int i = lo; i < hi; i++) s += deg[i];
    sh[t] = s;
    __syncthreads();
    for (int off = 1; off < 1024; off <<= 1) {
        int v = sh[t];
        int u = (t >= off) ? sh[t - off] : 0;
        __syncthreads();
        sh[t] = v + u;
        __syncthreads();
    }
    int run = (t == 0) ? 0 : sh[t - 1];
    for (int i = lo; i < hi; i++) {
        ptrArr[i] = run; cur[i] = run; run += deg[i];
    }
    if (t == 1023) ptrArr[n] = sh[1023];
}

__global__ void k_scatter(int* __restrict__ csr, int* __restrict__ cur,
                          const int* __restrict__ src, const int* __restrict__ dst, int E) {
    int i = blockIdx.x * blockDim.x + threadIdx.x;
    if (i < E) {
        int pos = atomicAdd(&cur[dst[i]], 1);
        csr[pos] = src[i];
    }
}

// ---------------- weight prep ----------------
// Bc1[500][160]: cols 0..127 = W_src1; 128..139 = al-proj (src h0-3, dst1 h0-3, dst21 h0-3); rest 0
__global__ void k_build_Bc1(const float* __restrict__ Ws, const float* __restrict__ Wd,
                            const float* __restrict__ Wd2, const float* __restrict__ as_,
                            const float* __restrict__ ad, const float* __restrict__ ad2,
                            float* __restrict__ Bc) {
    int t = blockIdx.x * blockDim.x + threadIdx.x;
    if (t >= 500 * 160) return;
    int k = t / 160, j = t % 160;
    float v = 0.f;
    if (j < 128) v = Ws[k * 128 + j];
    else if (j < 140) {
        int q = j - 128; int h = q & 3;
        const float* W; const float* a;
        if (q < 4)      { W = Ws;  a = as_; }
        else if (q < 8) { W = Wd;  a = ad;  }
        else            { W = Wd2; a = ad2; }
        float s = 0.f;
        #pragma unroll 8
        for (int c = 0; c < 32; c++) s += W[k * 128 + h * 32 + c] * a[h * 32 + c];
        v = s;
    }
    Bc[t] = v;
}

// Wc2[k][j], k<256, j<48: j<40 = W_src2[k][j]; 40..42 = al-projection cols; 43..47 = 0
__global__ void k_build_W2(const float* __restrict__ Ws, const float* __restrict__ Wd,
                           const float* __restrict__ Wd2, const float* __restrict__ as_,
                           const float* __restrict__ ad, const float* __restrict__ ad2,
                           float* __restrict__ Wc) {
    int t = blockIdx.x * blockDim.x + threadIdx.x;
    if (t >= 256 * 48) return;
    int k = t / 48, j = t % 48;
    float v = 0.f;
    if (j < 40) v = Ws[k * 40 + j];
    else if (j == 40) { for (int c = 0; c < 40; c++) v += Ws [k * 40 + c] * as_[c]; }
    else if (j == 41) { for (int c = 0; c < 40; c++) v += Wd [k * 40 + c] * ad [c]; }
    else if (j == 42) { for (int c = 0; c < 40; c++) v += Wd2[k * 40 + c] * ad2[c]; }
    Wc[k * 48 + j] = v;
}

// ---------------- GEMM with mixed bf16/fp32 epilogue ----------------
// MODE 1: XC=128 bf16 cols -> xb (stride 128), 16 fp32 cols -> alb (stride 16)
// MODE 2: XC=40  bf16 cols -> xb (stride 40),  3  fp32 cols -> alb (stride 4)
template <int BN, int MODE>
__global__ __launch_bounds__(256) void k_gemm(const float* __restrict__ A, int lda,
                                              const float* __restrict__ B,
                                              unsigned short* __restrict__ xb,
                                              float* __restrict__ alb,
                                              int M, int K) {
    constexpr int BM = 64, BK = 16;
    constexpr int TC = BN / 16;
    constexpr int XC  = (MODE == 1) ? 128 : 40;
    constexpr int AC  = (MODE == 1) ? 16 : 4;   // alb stride
    constexpr int ACN = (MODE == 1) ? 16 : 3;   // fp32 cols stored
    __shared__ float As[BM][BK + 1];
    __shared__ float Bs[BK][BN];
    int tid = threadIdx.x;
    int rowBlk = blockIdx.x * BM;
    int tr = tid >> 4, tc = tid & 15;
    float acc[4][TC];
    #pragma unroll
    for (int i = 0; i < 4; i++)
        #pragma unroll
        for (int j = 0; j < TC; j++) acc[i][j] = 0.f;

    for (int k0 = 0; k0 < K; k0 += BK) {
        int arow = tid >> 2, ac = (tid & 3) * 4;
        int gr = rowBlk + arow;
        #pragma unroll
        for (int i = 0; i < 4; i++) {
            int gk = k0 + ac + i;
            As[arow][ac + i] = (gr < M && gk < K) ? A[(size_t)gr * lda + gk] : 0.f;
        }
        int brow = tid >> 4, bc = (tid & 15) * TC;
        int gk = k0 + brow;
        #pragma unroll
        for (int j = 0; j < TC; j++)
            Bs[brow][bc + j] = (gk < K) ? B[(size_t)gk * BN + bc + j] : 0.f;
        __syncthreads();
        #pragma unroll
        for (int kk = 0; kk < BK; kk++) {
            float av[4], bv[TC];
            #pragma unroll
            for (int i = 0; i < 4; i++) av[i] = As[tr * 4 + i][kk];
            #pragma unroll
            for (int j = 0; j < TC; j++) bv[j] = Bs[kk][tc * TC + j];
            #pragma unroll
            for (int i = 0; i < 4; i++)
                #pragma unroll
                for (int j = 0; j < TC; j++) acc[i][j] += av[i] * bv[j];
        }
        __syncthreads();
    }
    #pragma unroll
    for (int i = 0; i < 4; i++) {
        int gr = rowBlk + tr * 4 + i;
        if (gr < M) {
            #pragma unroll
            for (int j = 0; j < TC; j++) {
                int col = tc * TC + j;
                float v = acc[i][j];
                if (col < XC) xb[(size_t)gr * XC + col] = f2bf(v);
                else if (col < XC + ACN) alb[(size_t)gr * AC + (col - XC)] = v;
            }
        }
    }
}

// ---------------- layer-1 propagate: H=4, C=32, bf16 gather, fused ELU -------
// al row layout (stride 16): [als(4) | ald1(4) | ald21(4) | pad]; doff = 4 or 8
__global__ __launch_bounds__(256) void k_prop1(const int* __restrict__ ptr, const int* __restrict__ csr,
                                               const float* __restrict__ al, int doff,
                                               const unsigned int* __restrict__ xb,
                                               float* __restrict__ out, int n) {
    int wid = (blockIdx.x * blockDim.x + threadIdx.x) >> 6;
    int lane = threadIdx.x & 63;
    if (wid >= n) return;
    int d = wid;
    int b = ptr[d], e = ptr[d + 1];
    const float4 adv = *(const float4*)&al[(size_t)d * 16 + doff];

    // pass 1: segment max (lane-parallel)
    float m0 = -INFINITY, m1 = -INFINITY, m2 = -INFINITY, m3 = -INFINITY;
    for (int p = b + lane; p < e; p += 64) {
        int s = csr[p];
        float4 av = *(const float4*)&al[(size_t)s * 16];
        float a0 = av.x + adv.x; a0 = a0 > 0.f ? a0 : 0.2f * a0; m0 = fmaxf(m0, a0);
        float a1 = av.y + adv.y; a1 = a1 > 0.f ? a1 : 0.2f * a1; m1 = fmaxf(m1, a1);
        float a2 = av.z + adv.z; a2 = a2 > 0.f ? a2 : 0.2f * a2; m2 = fmaxf(m2, a2);
        float a3 = av.w + adv.w; a3 = a3 > 0.f ? a3 : 0.2f * a3; m3 = fmaxf(m3, a3);
    }
    #pragma unroll
    for (int o = 32; o > 0; o >>= 1) {
        m0 = fmaxf(m0, __shfl_xor(m0, o));
        m1 = fmaxf(m1, __shfl_xor(m1, o));
        m2 = fmaxf(m2, __shfl_xor(m2, o));
        m3 = fmaxf(m3, __shfl_xor(m3, o));
    }

    // combined pass: per-chunk weight precompute + broadcast accumulate
    int h = lane >> 4;
    float den0 = 0.f, den1 = 0.f, den2 = 0.f, den3 = 0.f;
    float acc0 = 0.f, acc1 = 0.f;
    for (int cb = b; cb < e; cb += 64) {
        int cnt = min(64, e - cb);
        int s = 0; float w0 = 0.f, w1 = 0.f, w2 = 0.f, w3 = 0.f;
        if (lane < cnt) {
            s = csr[cb + lane];
            float4 av = *(const float4*)&al[(size_t)s * 16];
            float a0 = av.x + adv.x; a0 = a0 > 0.f ? a0 : 0.2f * a0; w0 = __expf(a0 - m0);
            float a1 = av.y + adv.y; a1 = a1 > 0.f ? a1 : 0.2f * a1; w1 = __expf(a1 - m1);
            float a2 = av.z + adv.z; a2 = a2 > 0.f ? a2 : 0.2f * a2; w2 = __expf(a2 - m2);
            float a3 = av.w + adv.w; a3 = a3 > 0.f ? a3 : 0.2f * a3; w3 = __expf(a3 - m3);
        }
        den0 += w0; den1 += w1; den2 += w2; den3 += w3;
        for (int j = 0; j < cnt; j++) {
            int sj = __shfl(s, j);
            float wa = __shfl(w0, j), wb = __shfl(w1, j);
            float wc = __shfl(w2, j), wd = __shfl(w3, j);
            float wv = (h == 0) ? wa : (h == 1) ? wb : (h == 2) ? wc : wd;
            unsigned int pk = xb[(size_t)sj * 64 + lane];
            acc0 += wv * __uint_as_float(pk << 16);
            acc1 += wv * __uint_as_float(pk & 0xffff0000u);
        }
    }
    #pragma unroll
    for (int o = 32; o > 0; o >>= 1) {
        den0 += __shfl_xor(den0, o);
        den1 += __shfl_xor(den1, o);
        den2 += __shfl_xor(den2, o);
        den3 += __shfl_xor(den3, o);
    }
    float dh = (h == 0) ? den0 : (h == 1) ? den1 : (h == 2) ? den2 : den3;
    float inv = 1.f / (dh + 1e-16f);
    float r0 = acc0 * inv, r1 = acc1 * inv;
    r0 = r0 > 0.f ? r0 : __expf(r0) - 1.f;   // ELU
    r1 = r1 > 0.f ? r1 : __expf(r1) - 1.f;
    float2 st; st.x = r0; st.y = r1;
    *(float2*)&out[(size_t)d * 256 + 2 * lane] = st;
}

// ---------------- layer-2 propagate: H=1, C=40, bf16 gather, 3 edges/iter ----
// al row layout (stride 4): [als | ald1 | ald22 | pad]; didx = 1 or 2
__global__ __launch_bounds__(256) void k_prop2(const int* __restrict__ ptr, const int* __restrict__ csr,
                                               const float* __restrict__ al, int didx,
                                               const unsigned int* __restrict__ xb,
                                               float* __restrict__ out, int n) {
    int wid = (blockIdx.x * blockDim.x + threadIdx.x) >> 6;
    int lane = threadIdx.x & 63;
    if (wid >= n) return;
    int d = wid;
    int b = ptr[d], e = ptr[d + 1];
    float ad = al[(size_t)d * 4 + didx];

    float m = -INFINITY;
    for (int p = b + lane; p < e; p += 64) {
        int s = csr[p];
        float a = al[(size_t)s * 4] + ad;
        a = a > 0.f ? a : 0.2f * a;
        m = fmaxf(m, a);
    }
    #pragma unroll
    for (int o = 32; o > 0; o >>= 1) m = fmaxf(m, __shfl_xor(m, o));

    int grp = lane / 20;          // 0..3 (grp 3 = lanes 60-63, compute-idle)
    int cp  = lane - grp * 20;    // channel pair 0..19
    float den = 0.f, acc0 = 0.f, acc1 = 0.f;
    for (int cb = b; cb < e; cb += 64) {
        int cnt = min(64, e - cb);
        int s = 0; float w = 0.f;
        if (lane < cnt) {
            s = csr[cb + lane];
            float a = al[(size_t)s * 4] + ad;
            a = a > 0.f ? a : 0.2f * a;
            w = __expf(a - m);
        }
        den += w;
        int nit = (cnt + 2) / 3;
        for (int j = 0; j < nit; j++) {
            int ei = j * 3 + grp;
            bool v = (grp < 3) && (ei < cnt);
            int eic = v ? ei : 0;
            float wj = __shfl(w, eic); if (!v) wj = 0.f;
            int sj = __shfl(s, eic);
            unsigned int pk = xb[(size_t)sj * 20 + cp];
            acc0 += wj * __uint_as_float(pk << 16);
            acc1 += wj * __uint_as_float(pk & 0xffff0000u);
        }
    }
    #pragma unroll
    for (int o = 32; o > 0; o >>= 1) den += __shfl_xor(den, o);
    // cross-group reduce (results valid on lanes 0..19)
    acc0 += __shfl(acc0, (lane + 20) & 63) + __shfl(acc0, (lane + 40) & 63);
    acc1 += __shfl(acc1, (lane + 20) & 63) + __shfl(acc1, (lane + 40) & 63);
    if (lane < 20) {
        float inv = 1.f / (den + 1e-16f);
        float2 st; st.x = acc0 * inv; st.y = acc1 * inv;
        *(float2*)&out[(size_t)d * 80 + 2 * cp] = st;
    }
}

// ---------------- log_softmax over 80 cols, one wave per row ----------------
__global__ __launch_bounds__(256) void k_lsm(const float* __restrict__ h2, float* __restrict__ out, int n) {
    int wid = (blockIdx.x * blockDim.x + threadIdx.x) >> 6;
    int lane = threadIdx.x & 63;
    if (wid >= n) return;
    const float* row = h2 + (size_t)wid * 80;
    float v0 = row[lane];
    float v1 = (lane < 16) ? row[64 + lane] : -INFINITY;
    float m = fmaxf(v0, v1);
    for (int o = 32; o > 0; o >>= 1) m = fmaxf(m, __shfl_xor(m, o));
    float s = __expf(v0 - m) + ((lane < 16) ? __expf(v1 - m) : 0.f);
    for (int o = 32; o > 0; o >>= 1) s += __shfl_xor(s, o);
    float ls = m + logf(s);
    out[(size_t)wid * 80 + lane] = v0 - ls;
    if (lane < 16) out[(size_t)wid * 80 + 64 + lane] = v1 - ls;
}

// ---------------- launch ----------------

extern "C" void kernel_launch(void* const* d_in, const int* in_sizes, int n_in,
                              void* d_out, int out_size, void* d_ws, size_t ws_size,
                              hipStream_t stream) {
    const float* x       = (const float*)d_in[0];
    const int*   e1      = (const int*)d_in[1];
    const int*   e2      = (const int*)d_in[2];
    const float* W_src1  = (const float*)d_in[3];
    const float* W_dst1  = (const float*)d_in[4];
    const float* W_dst21 = (const float*)d_in[5];
    const float* a_src1  = (const float*)d_in[6];
    const float* a_dst1  = (const float*)d_in[7];
    const float* a_dst21 = (const float*)d_in[8];
    const float* W_src2  = (const float*)d_in[9];
    const float* W_dst2  = (const float*)d_in[10];
    const float* W_dst22 = (const float*)d_in[11];
    const float* a_src2  = (const float*)d_in[12];
    const float* a_dst2  = (const float*)d_in[13];
    const float* a_dst22 = (const float*)d_in[14];
    float* out = (float*)d_out;

    const int FIN = 500;
    int n  = in_sizes[0] / FIN;     // 50000
    int E1 = in_sizes[1] / 2;       // 300000
    int E2 = in_sizes[2] / 2;       // ~1.7M
    const int* src1 = e1, *dst1 = e1 + E1;
    const int* src2 = e2, *dst2 = e2 + E2;

    char* w = (char*)d_ws;
    auto alloc = [&](size_t bytes) -> char* {
        char* p = w; w += (bytes + 255) & ~(size_t)255; return p;
    };
    unsigned short* xb1 = (unsigned short*)alloc((size_t)n * 128 * 2); // layer1 feats bf16
    float* alb1 = (float*)alloc((size_t)n * 16 * 4);                   // [als(4)|ald1(4)|ald21(4)|pad]
    float* hbuf = (float*)alloc((size_t)n * 256 * 4);                  // elu(concat) hidden fp32
    unsigned short* xb2 = (unsigned short*)alloc((size_t)n * 40 * 2);  // layer2 feats bf16
    float* alb2 = (float*)alloc((size_t)n * 4 * 4);                    // [als|ald1|ald22|pad]
    float* h2   = (float*)alloc((size_t)n * 80 * 4);                   // pre-logsoftmax
    float* Bc1  = (float*)alloc(500 * 160 * 4);
    float* Wc2  = (float*)alloc(256 * 48 * 4);
    int* ptr1 = (int*)alloc((size_t)(n + 1) * 4);
    int* cur1 = (int*)alloc((size_t)n * 4);
    int* deg1 = (int*)alloc((size_t)n * 4);
    int* csr1 = (int*)alloc((size_t)E1 * 4);
    int* ptr2 = (int*)alloc((size_t)(n + 1) * 4);
    int* cur2 = (int*)alloc((size_t)n * 4);
    int* deg2 = (int*)alloc((size_t)n * 4);
    int* csr2 = (int*)alloc((size_t)E2 * 4);

    // CSR build
    hipMemsetAsync(deg1, 0, (size_t)n * 4, stream);
    hipMemsetAsync(deg2, 0, (size_t)n * 4, stream);
    k_hist<<<(E1 + 255) / 256, 256, 0, stream>>>(deg1, dst1, E1);
    k_hist<<<(E2 + 255) / 256, 256, 0, stream>>>(deg2, dst2, E2);
    k_scan<<<1, 1024, 0, stream>>>(deg1, ptr1, cur1, n);
    k_scan<<<1, 1024, 0, stream>>>(deg2, ptr2, cur2, n);
    k_scatter<<<(E1 + 255) / 256, 256, 0, stream>>>(csr1, cur1, src1, dst1, E1);
    k_scatter<<<(E2 + 255) / 256, 256, 0, stream>>>(csr2, cur2, src2, dst2, E2);

    // layer 1 linear (fused features + attention-logit projections)
    k_build_Bc1<<<(500 * 160 + 255) / 256, 256, 0, stream>>>(W_src1, W_dst1, W_dst21,
                                                             a_src1, a_dst1, a_dst21, Bc1);
    k_gemm<160, 1><<<(n + 63) / 64, 256, 0, stream>>>(x, FIN, Bc1, xb1, alb1, n, FIN);

    // layer 1 propagate (+ fused ELU)
    int pblocks = (n + 3) / 4;
    k_prop1<<<pblocks, 256, 0, stream>>>(ptr1, csr1, alb1, 4, (const unsigned int*)xb1,
                                         hbuf + 0, n);
    k_prop1<<<pblocks, 256, 0, stream>>>(ptr2, csr2, alb1, 8, (const unsigned int*)xb1,
                                         hbuf + 128, n);

    // layer 2 linear
    k_build_W2<<<(256 * 48 + 255) / 256, 256, 0, stream>>>(W_src2, W_dst2, W_dst22,
                                                           a_src2, a_dst2, a_dst22, Wc2);
    k_gemm<48, 2><<<(n + 63) / 64, 256, 0, stream>>>(hbuf, 256, Wc2, xb2, alb2, n, 256);

    // layer 2 propagate
    k_prop2<<<pblocks, 256, 0, stream>>>(ptr1, csr1, alb2, 1, (const unsigned int*)xb2,
                                         h2 + 0, n);
    k_prop2<<<pblocks, 256, 0, stream>>>(ptr2, csr2, alb2, 2, (const unsigned int*)xb2,
                                         h2 + 40, n);

    // log_softmax
    k_lsm<<<pblocks, 256, 0, stream>>>(h2, out, n);
}

// Round 3
// 631.154 us; speedup vs baseline: 1.9470x; 1.4566x over previous
//
#include <hip/hip_runtime.h>
#include <hip/hip_bf16.h>
#include <math.h>

typedef unsigned short u16;
typedef unsigned int u32;
typedef __attribute__((ext_vector_type(8))) short short8;
typedef __attribute__((ext_vector_type(4))) float f32x4;

static __device__ __forceinline__ u16 f2bf(float f) {
    u32 u = __float_as_uint(f);
    u32 r = (u + 0x7fffu + ((u >> 16) & 1u)) >> 16;
    return (u16)r;
}
static __device__ __forceinline__ float bl(u32 u) { return __uint_as_float(u << 16); }
static __device__ __forceinline__ float bh(u32 u) { return __uint_as_float(u & 0xffff0000u); }

// ---------------- CSR build ----------------

__global__ void k_hist(int* __restrict__ deg, const int* __restrict__ dst, int E) {
    int i = blockIdx.x * blockDim.x + threadIdx.x;
    if (i < E) atomicAdd(&deg[dst[i]], 1);
}

__global__ void k_scan(const int* __restrict__ deg, int* __restrict__ ptrArr,
                       int* __restrict__ cur, int n) {
    __shared__ int sh[1024];
    int t = threadIdx.x;
    int chunk = (n + 1023) / 1024;
    int lo = t * chunk;
    int hi = lo + chunk; if (hi > n) hi = n; if (lo > n) lo = n;
    int s = 0;
    for (int i = lo; i < hi; i++) s += deg[i];
    sh[t] = s;
    __syncthreads();
    for (int off = 1; off < 1024; off <<= 1) {
        int v = sh[t];
        int u = (t >= off) ? sh[t - off] : 0;
        __syncthreads();
        sh[t] = v + u;
        __syncthreads();
    }
    int run = (t == 0) ? 0 : sh[t - 1];
    for (int i = lo; i < hi; i++) {
        ptrArr[i] = run; cur[i] = run; run += deg[i];
    }
    if (t == 1023) ptrArr[n] = sh[1023];
}

__global__ void k_scatter(int* __restrict__ csr, int* __restrict__ cur,
                          const int* __restrict__ src, const int* __restrict__ dst, int E) {
    int i = blockIdx.x * blockDim.x + threadIdx.x;
    if (i < E) {
        int pos = atomicAdd(&cur[dst[i]], 1);
        csr[pos] = src[i];
    }
}

// ---------------- weight prep (transposed bf16 B matrices) ----------------
// Bt1[144][512] bf16, n-major: n<128 = W_src1[k][n]; 128..139 = al-proj cols; 140..143,k>=500 = 0
__global__ void k_build_Bt1(const float* __restrict__ Ws, const float* __restrict__ Wd,
                            const float* __restrict__ Wd2, const float* __restrict__ as_,
                            const float* __restrict__ ad, const float* __restrict__ ad2,
                            u16* __restrict__ Bt) {
    int t = blockIdx.x * blockDim.x + threadIdx.x;
    if (t >= 144 * 512) return;
    int nn = t >> 9, k = t & 511;
    float v = 0.f;
    if (k < 500) {
        if (nn < 128) v = Ws[k * 128 + nn];
        else if (nn < 140) {
            int q = nn - 128; int h = q & 3;
            const float* W; const float* a;
            if (q < 4)      { W = Ws;  a = as_; }
            else if (q < 8) { W = Wd;  a = ad;  }
            else            { W = Wd2; a = ad2; }
            float s = 0.f;
            #pragma unroll 8
            for (int c = 0; c < 32; c++) s += W[k * 128 + h * 32 + c] * a[h * 32 + c];
            v = s;
        }
    }
    Bt[t] = f2bf(v);
}

// Bt2[48][256] bf16, n-major: n<40 = W_src2[k][n]; 40..42 = al-proj; 43..47 = 0
__global__ void k_build_Bt2(const float* __restrict__ Ws, const float* __restrict__ Wd,
                            const float* __restrict__ Wd2, const float* __restrict__ as_,
                            const float* __restrict__ ad, const float* __restrict__ ad2,
                            u16* __restrict__ Bt) {
    int t = blockIdx.x * blockDim.x + threadIdx.x;
    if (t >= 48 * 256) return;
    int nn = t >> 8, k = t & 255;
    float v = 0.f;
    if (nn < 40) v = Ws[k * 40 + nn];
    else if (nn < 43) {
        const float* a = (nn == 40) ? as_ : (nn == 41) ? ad : ad2;
        const float* W = Ws;
        if (nn == 41) W = Wd; else if (nn == 42) W = Wd2;
        float s = 0.f;
        #pragma unroll 8
        for (int c = 0; c < 40; c++) s += W[k * 40 + c] * a[c];
        v = s;
    }
    Bt[t] = f2bf(v);
}

// ---------------- MFMA GEMM layer 1: A=x fp32 [M][500], Bt1 bf16 [144][512] ----
// out: cols 0..127 -> xb bf16 [M][128]; cols 128..139 -> alb fp32 stride 16
__global__ __launch_bounds__(256) void k_mgemm1(const float* __restrict__ A,
                                                const u16* __restrict__ Bt,
                                                u16* __restrict__ xb,
                                                float* __restrict__ alb, int M) {
    __shared__ __align__(16) u16 As[64][40];
    __shared__ __align__(16) u16 Bs[144][40];
    int tid = threadIdx.x;
    int wv = tid >> 6, lane = tid & 63;
    int l15 = lane & 15, k8 = lane >> 4;
    int rowBlk = blockIdx.x * 64;

    f32x4 acc[9];
    #pragma unroll
    for (int t = 0; t < 9; t++) acc[t] = (f32x4){0.f, 0.f, 0.f, 0.f};

    int r = tid >> 2, kc = (tid & 3) * 8;
    bool rowOK = (rowBlk + r) < M;
    const float* Ap0 = A + (size_t)(rowBlk + r) * 500;

    for (int k0 = 0; k0 < 512; k0 += 32) {
        // stage A (fp32 -> bf16)
        float v[8];
        const float* Ap = Ap0 + k0 + kc;
        if (rowOK && (k0 + kc + 8 <= 500)) {
            float4 p0 = *(const float4*)Ap;
            float4 p1 = *(const float4*)(Ap + 4);
            v[0] = p0.x; v[1] = p0.y; v[2] = p0.z; v[3] = p0.w;
            v[4] = p1.x; v[5] = p1.y; v[6] = p1.z; v[7] = p1.w;
        } else {
            #pragma unroll
            for (int i = 0; i < 8; i++) {
                int gk = k0 + kc + i;
                v[i] = (rowOK && gk < 500) ? Ap[i] : 0.f;
            }
        }
        uint4 pk;
        pk.x = (u32)f2bf(v[0]) | ((u32)f2bf(v[1]) << 16);
        pk.y = (u32)f2bf(v[2]) | ((u32)f2bf(v[3]) << 16);
        pk.z = (u32)f2bf(v[4]) | ((u32)f2bf(v[5]) << 16);
        pk.w = (u32)f2bf(v[6]) | ((u32)f2bf(v[7]) << 16);
        *(uint4*)&As[r][kc] = pk;
        // stage B (144 rows x 32 k)
        for (int idx = tid; idx < 144 * 4; idx += 256) {
            int nn = idx >> 2, c = (idx & 3) * 8;
            *(uint4*)&Bs[nn][c] = *(const uint4*)&Bt[nn * 512 + k0 + c];
        }
        __syncthreads();
        short8 af = *(const short8*)&As[wv * 16 + l15][k8 * 8];
        #pragma unroll
        for (int t = 0; t < 9; t++) {
            short8 bf = *(const short8*)&Bs[t * 16 + l15][k8 * 8];
            acc[t] = __builtin_amdgcn_mfma_f32_16x16x32_bf16(af, bf, acc[t], 0, 0, 0);
        }
        __syncthreads();
    }
    #pragma unroll
    for (int t = 0; t < 9; t++) {
        #pragma unroll
        for (int rr = 0; rr < 4; rr++) {
            int grow = rowBlk + wv * 16 + k8 * 4 + rr;
            if (grow < M) {
                if (t < 8) {
                    xb[(size_t)grow * 128 + t * 16 + l15] = f2bf(acc[t][rr]);
                } else if (l15 < 12) {
                    alb[(size_t)grow * 16 + l15] = acc[t][rr];
                }
            }
        }
    }
}

// ---------------- MFMA GEMM layer 2: A=hbuf bf16 [M][256], Bt2 bf16 [48][256] --
// out: cols 0..39 -> xb bf16 [M][40]; cols 40..42 -> alb fp32 stride 4
__global__ __launch_bounds__(256) void k_mgemm2(const u16* __restrict__ A,
                                                const u16* __restrict__ Bt,
                                                u16* __restrict__ xb,
                                                float* __restrict__ alb, int M) {
    __shared__ __align__(16) u16 As[64][40];
    __shared__ __align__(16) u16 Bs[48][40];
    int tid = threadIdx.x;
    int wv = tid >> 6, lane = tid & 63;
    int l15 = lane & 15, k8 = lane >> 4;
    int rowBlk = blockIdx.x * 64;

    f32x4 acc[3];
    #pragma unroll
    for (int t = 0; t < 3; t++) acc[t] = (f32x4){0.f, 0.f, 0.f, 0.f};

    int r = tid >> 2, kc = (tid & 3) * 8;
    bool rowOK = (rowBlk + r) < M;
    const u16* Ap0 = A + (size_t)(rowBlk + r) * 256;

    for (int k0 = 0; k0 < 256; k0 += 32) {
        uint4 pk = {0, 0, 0, 0};
        if (rowOK) pk = *(const uint4*)(Ap0 + k0 + kc);
        *(uint4*)&As[r][kc] = pk;
        if (tid < 48 * 4) {
            int nn = tid >> 2, c = (tid & 3) * 8;
            *(uint4*)&Bs[nn][c] = *(const uint4*)&Bt[nn * 256 + k0 + c];
        }
        __syncthreads();
        short8 af = *(const short8*)&As[wv * 16 + l15][k8 * 8];
        #pragma unroll
        for (int t = 0; t < 3; t++) {
            short8 bf = *(const short8*)&Bs[t * 16 + l15][k8 * 8];
            acc[t] = __builtin_amdgcn_mfma_f32_16x16x32_bf16(af, bf, acc[t], 0, 0, 0);
        }
        __syncthreads();
    }
    #pragma unroll
    for (int t = 0; t < 3; t++) {
        #pragma unroll
        for (int rr = 0; rr < 4; rr++) {
            int grow = rowBlk + wv * 16 + k8 * 4 + rr;
            if (grow < M) {
                int col = t * 16 + l15;
                if (col < 40) xb[(size_t)grow * 40 + col] = f2bf(acc[t][rr]);
                else if (col < 43) alb[(size_t)grow * 4 + (col - 40)] = acc[t][rr];
            }
        }
    }
}

// ---------------- layer-1 propagate: H=4, C=32, no-max softmax, fused ELU -----
// al stride 16: [als(4)|ald1(4)|ald21(4)|pad]; doff 4 or 8. out bf16 stride 256.
__global__ __launch_bounds__(256) void k_prop1(const int* __restrict__ ptr, const int* __restrict__ csr,
                                               const float* __restrict__ al, int doff,
                                               const uint2* __restrict__ xbv,
                                               u16* __restrict__ out, int n) {
    __shared__ int sbuf[4][64];
    __shared__ __align__(16) float wbuf[4][64][4];
    int tid = threadIdx.x;
    int wv = tid >> 6, lane = tid & 63;
    int wid = (blockIdx.x * 256 + tid) >> 6;
    if (wid >= n) return;
    int b = ptr[wid], e = ptr[wid + 1];
    float4 adv = *(const float4*)(al + (size_t)wid * 16 + doff);
    int l5 = lane & 31, h2 = l5 >> 3, half = lane >> 5;

    float acc0 = 0.f, acc1 = 0.f, acc2 = 0.f, acc3 = 0.f;
    float dn0 = 0.f, dn1 = 0.f, dn2 = 0.f, dn3 = 0.f;

    for (int cb = b; cb < e; cb += 64) {
        int cnt = min(64, e - cb);
        int s = 0;
        float w0 = 0.f, w1 = 0.f, w2 = 0.f, w3 = 0.f;
        if (lane < cnt) {
            s = csr[cb + lane];
            float4 av = *(const float4*)(al + (size_t)s * 16);
            float a0 = av.x + adv.x; a0 = a0 > 0.f ? a0 : 0.2f * a0; w0 = __expf(a0);
            float a1 = av.y + adv.y; a1 = a1 > 0.f ? a1 : 0.2f * a1; w1 = __expf(a1);
            float a2 = av.z + adv.z; a2 = a2 > 0.f ? a2 : 0.2f * a2; w2 = __expf(a2);
            float a3 = av.w + adv.w; a3 = a3 > 0.f ? a3 : 0.2f * a3; w3 = __expf(a3);
        }
        dn0 += w0; dn1 += w1; dn2 += w2; dn3 += w3;
        sbuf[wv][lane] = s;
        float4 wq; wq.x = w0; wq.y = w1; wq.z = w2; wq.w = w3;
        *(float4*)&wbuf[wv][lane][0] = wq;
        #pragma unroll 4
        for (int j = 0; j < cnt; j += 2) {
            int jj = j + half;              // half 1 may read j==cnt (odd tail): w=0 there
            int sj = sbuf[wv][jj];
            float wj = wbuf[wv][jj][h2];
            uint2 pk = xbv[(size_t)sj * 32 + l5];
            acc0 = fmaf(wj, bl(pk.x), acc0);
            acc1 = fmaf(wj, bh(pk.x), acc1);
            acc2 = fmaf(wj, bl(pk.y), acc2);
            acc3 = fmaf(wj, bh(pk.y), acc3);
        }
    }
    acc0 += __shfl_xor(acc0, 32);
    acc1 += __shfl_xor(acc1, 32);
    acc2 += __shfl_xor(acc2, 32);
    acc3 += __shfl_xor(acc3, 32);
    #pragma unroll
    for (int o = 32; o > 0; o >>= 1) {
        dn0 += __shfl_xor(dn0, o);
        dn1 += __shfl_xor(dn1, o);
        dn2 += __shfl_xor(dn2, o);
        dn3 += __shfl_xor(dn3, o);
    }
    float dh = (h2 == 0) ? dn0 : (h2 == 1) ? dn1 : (h2 == 2) ? dn2 : dn3;
    float inv = 1.f / (dh + 1e-16f);
    float r0 = acc0 * inv, r1 = acc1 * inv, r2 = acc2 * inv, r3 = acc3 * inv;
    r0 = r0 > 0.f ? r0 : __expf(r0) - 1.f;
    r1 = r1 > 0.f ? r1 : __expf(r1) - 1.f;
    r2 = r2 > 0.f ? r2 : __expf(r2) - 1.f;
    r3 = r3 > 0.f ? r3 : __expf(r3) - 1.f;
    if (half == 0) {
        uint2 st;
        st.x = (u32)f2bf(r0) | ((u32)f2bf(r1) << 16);
        st.y = (u32)f2bf(r2) | ((u32)f2bf(r3) << 16);
        *(uint2*)(out + (size_t)wid * 256 + 4 * l5) = st;
    }
}

// ---------------- layer-2 propagate: H=1, C=40, no-max softmax ----------------
// al stride 4: [als|ald1|ald22|pad]; didx 1 or 2. out fp32 stride 80 (base pre-offset).
__global__ __launch_bounds__(256) void k_prop2(const int* __restrict__ ptr, const int* __restrict__ csr,
                                               const float* __restrict__ al, int didx,
                                               const uint2* __restrict__ xbv,
                                               float* __restrict__ out, int n) {
    __shared__ int2 swb[4][64];
    int tid = threadIdx.x;
    int wv = tid >> 6, lane = tid & 63;
    int wid = (blockIdx.x * 256 + tid) >> 6;
    if (wid >= n) return;
    int b = ptr[wid], e = ptr[wid + 1];
    float ad = al[(size_t)wid * 4 + didx];
    int g = lane / 10;            // 0..6 (g==6: lanes 60..63 idle)
    int cp = lane - g * 10;       // 0..9
    bool act = g < 6;

    float acc0 = 0.f, acc1 = 0.f, acc2 = 0.f, acc3 = 0.f;
    float den = 0.f;

    for (int cb = b; cb < e; cb += 64) {
        int cnt = min(64, e - cb);
        int s = 0; float w = 0.f;
        if (lane < cnt) {
            s = csr[cb + lane];
            float a = al[(size_t)s * 4] + ad;
            a = a > 0.f ? a : 0.2f * a;
            w = __expf(a);
        }
        den += w;
        swb[wv][lane] = make_int2(s, __float_as_int(w));
        #pragma unroll 2
        for (int j = 0; j < cnt; j += 6) {
            int jj = j + g;
            bool valid = act && (jj < cnt);
            int2 sw = swb[wv][valid ? jj : 0];
            float wj = valid ? __int_as_float(sw.y) : 0.f;
            uint2 pk = xbv[(size_t)sw.x * 10 + cp];
            acc0 = fmaf(wj, bl(pk.x), acc0);
            acc1 = fmaf(wj, bh(pk.x), acc1);
            acc2 = fmaf(wj, bl(pk.y), acc2);
            acc3 = fmaf(wj, bh(pk.y), acc3);
        }
    }
    // reduce 6 groups -> group 0 (lanes 0..9)
    float t0;
    t0 = acc0 + __shfl(acc0, (lane + 30) & 63); acc0 = t0 + __shfl(t0, (lane + 10) & 63) + __shfl(t0, (lane + 20) & 63);
    t0 = acc1 + __shfl(acc1, (lane + 30) & 63); acc1 = t0 + __shfl(t0, (lane + 10) & 63) + __shfl(t0, (lane + 20) & 63);
    t0 = acc2 + __shfl(acc2, (lane + 30) & 63); acc2 = t0 + __shfl(t0, (lane + 10) & 63) + __shfl(t0, (lane + 20) & 63);
    t0 = acc3 + __shfl(acc3, (lane + 30) & 63); acc3 = t0 + __shfl(t0, (lane + 10) & 63) + __shfl(t0, (lane + 20) & 63);
    #pragma unroll
    for (int o = 32; o > 0; o >>= 1) den += __shfl_xor(den, o);
    if (lane < 10) {
        float inv = 1.f / (den + 1e-16f);
        float4 st; st.x = acc0 * inv; st.y = acc1 * inv; st.z = acc2 * inv; st.w = acc3 * inv;
        *(float4*)(out + (size_t)wid * 80 + 4 * cp) = st;
    }
}

// ---------------- log_softmax over 80 cols, one wave per row ----------------
__global__ __launch_bounds__(256) void k_lsm(const float* __restrict__ h2, float* __restrict__ out, int n) {
    int wid = (blockIdx.x * blockDim.x + threadIdx.x) >> 6;
    int lane = threadIdx.x & 63;
    if (wid >= n) return;
    const float* row = h2 + (size_t)wid * 80;
    float v0 = row[lane];
    float v1 = (lane < 16) ? row[64 + lane] : -INFINITY;
    float m = fmaxf(v0, v1);
    for (int o = 32; o > 0; o >>= 1) m = fmaxf(m, __shfl_xor(m, o));
    float s = __expf(v0 - m) + ((lane < 16) ? __expf(v1 - m) : 0.f);
    for (int o = 32; o > 0; o >>= 1) s += __shfl_xor(s, o);
    float ls = m + logf(s);
    out[(size_t)wid * 80 + lane] = v0 - ls;
    if (lane < 16) out[(size_t)wid * 80 + 64 + lane] = v1 - ls;
}

// ---------------- launch ----------------

extern "C" void kernel_launch(void* const* d_in, const int* in_sizes, int n_in,
                              void* d_out, int out_size, void* d_ws, size_t ws_size,
                              hipStream_t stream) {
    const float* x       = (const float*)d_in[0];
    const int*   e1      = (const int*)d_in[1];
    const int*   e2      = (const int*)d_in[2];
    const float* W_src1  = (const float*)d_in[3];
    const float* W_dst1  = (const float*)d_in[4];
    const float* W_dst21 = (const float*)d_in[5];
    const float* a_src1  = (const float*)d_in[6];
    const float* a_dst1  = (const float*)d_in[7];
    const float* a_dst21 = (const float*)d_in[8];
    const float* W_src2  = (const float*)d_in[9];
    const float* W_dst2  = (const float*)d_in[10];
    const float* W_dst22 = (const float*)d_in[11];
    const float* a_src2  = (const float*)d_in[12];
    const float* a_dst2  = (const float*)d_in[13];
    const float* a_dst22 = (const float*)d_in[14];
    float* out = (float*)d_out;

    const int FIN = 500;
    int n  = in_sizes[0] / FIN;     // 50000
    int E1 = in_sizes[1] / 2;       // 300000
    int E2 = in_sizes[2] / 2;       // ~1.7M
    const int* src1 = e1, *dst1 = e1 + E1;
    const int* src2 = e2, *dst2 = e2 + E2;

    char* w = (char*)d_ws;
    auto alloc = [&](size_t bytes) -> char* {
        char* p = w; w += (bytes + 255) & ~(size_t)255; return p;
    };
    u16*   xb1  = (u16*)alloc((size_t)n * 128 * 2);   // layer1 feats bf16 [n][128]
    float* alb1 = (float*)alloc((size_t)n * 16 * 4);  // [als(4)|ald1(4)|ald21(4)|pad]
    u16*   hbuf = (u16*)alloc((size_t)n * 256 * 2);   // elu(concat) hidden bf16 [n][256]
    u16*   xb2  = (u16*)alloc((size_t)n * 40 * 2);    // layer2 feats bf16 [n][40]
    float* alb2 = (float*)alloc((size_t)n * 4 * 4);   // [als|ald1|ald22|pad]
    float* h2   = (float*)alloc((size_t)n * 80 * 4);  // pre-logsoftmax fp32
    u16*   Bt1  = (u16*)alloc(144 * 512 * 2);
    u16*   Bt2  = (u16*)alloc(48 * 256 * 2);
    int* ptr1 = (int*)alloc((size_t)(n + 1) * 4);
    int* cur1 = (int*)alloc((size_t)n * 4);
    int* deg1 = (int*)alloc((size_t)n * 4);
    int* csr1 = (int*)alloc((size_t)E1 * 4);
    int* ptr2 = (int*)alloc((size_t)(n + 1) * 4);
    int* cur2 = (int*)alloc((size_t)n * 4);
    int* deg2 = (int*)alloc((size_t)n * 4);
    int* csr2 = (int*)alloc((size_t)E2 * 4);

    // CSR build
    hipMemsetAsync(deg1, 0, (size_t)n * 4, stream);
    hipMemsetAsync(deg2, 0, (size_t)n * 4, stream);
    k_hist<<<(E1 + 255) / 256, 256, 0, stream>>>(deg1, dst1, E1);
    k_hist<<<(E2 + 255) / 256, 256, 0, stream>>>(deg2, dst2, E2);
    k_scan<<<1, 1024, 0, stream>>>(deg1, ptr1, cur1, n);
    k_scan<<<1, 1024, 0, stream>>>(deg2, ptr2, cur2, n);
    k_scatter<<<(E1 + 255) / 256, 256, 0, stream>>>(csr1, cur1, src1, dst1, E1);
    k_scatter<<<(E2 + 255) / 256, 256, 0, stream>>>(csr2, cur2, src2, dst2, E2);

    // layer 1: fused MFMA GEMM (features + attention-logit projections)
    k_build_Bt1<<<(144 * 512 + 255) / 256, 256, 0, stream>>>(W_src1, W_dst1, W_dst21,
                                                             a_src1, a_dst1, a_dst21, Bt1);
    k_mgemm1<<<(n + 63) / 64, 256, 0, stream>>>(x, Bt1, xb1, alb1, n);

    // layer 1 propagate (+ fused ELU), bf16 hidden out
    int pblocks = (n + 3) / 4;
    k_prop1<<<pblocks, 256, 0, stream>>>(ptr1, csr1, alb1, 4, (const uint2*)xb1, hbuf + 0, n);
    k_prop1<<<pblocks, 256, 0, stream>>>(ptr2, csr2, alb1, 8, (const uint2*)xb1, hbuf + 128, n);

    // layer 2: MFMA GEMM on bf16 hidden
    k_build_Bt2<<<(48 * 256 + 255) / 256, 256, 0, stream>>>(W_src2, W_dst2, W_dst22,
                                                            a_src2, a_dst2, a_dst22, Bt2);
    k_mgemm2<<<(n + 63) / 64, 256, 0, stream>>>(hbuf, Bt2, xb2, alb2, n);

    // layer 2 propagate
    k_prop2<<<pblocks, 256, 0, stream>>>(ptr1, csr1, alb2, 1, (const uint2*)xb2, h2 + 0, n);
    k_prop2<<<pblocks, 256, 0, stream>>>(ptr2, csr2, alb2, 2, (const uint2*)xb2, h2 + 40, n);

    // log_softmax
    k_lsm<<<pblocks, 256, 0, stream>>>(h2, out, n);
}

// Round 4
// 594.158 us; speedup vs baseline: 2.0682x; 1.0623x over previous
//
#include <hip/hip_runtime.h>
#include <hip/hip_bf16.h>
#include <math.h>

typedef unsigned short u16;
typedef unsigned int u32;
typedef __attribute__((ext_vector_type(8))) short short8;
typedef __attribute__((ext_vector_type(4))) float f32x4;

#define NB 128  // bucket slots (actual buckets = ceil(n/512) = 98 for n=50000)

static __device__ __forceinline__ u16 f2bf(float f) {
    u32 u = __float_as_uint(f);
    u32 r = (u + 0x7fffu + ((u >> 16) & 1u)) >> 16;
    return (u16)r;
}
static __device__ __forceinline__ float bl(u32 u) { return __uint_as_float(u << 16); }
static __device__ __forceinline__ float bh(u32 u) { return __uint_as_float(u & 0xffff0000u); }

// ---------------- CSR build ----------------

__global__ void k_hist(int* __restrict__ deg, const int* __restrict__ dst, int E) {
    int i = blockIdx.x * blockDim.x + threadIdx.x;
    if (i < E) atomicAdd(&deg[dst[i]], 1);
}

// single-block scan: deg -> ptr, cur; also bucket bases bcur[b] = ptr[b*512]
__global__ void k_scan(const int* __restrict__ deg, int* __restrict__ ptrArr,
                       int* __restrict__ cur, int* __restrict__ bcur, int n) {
    __shared__ int sh[1024];
    int t = threadIdx.x;
    int chunk = (n + 1023) / 1024;
    int lo = t * chunk;
    int hi = lo + chunk; if (hi > n) hi = n; if (lo > n) lo = n;
    int s = 0;
    for (int i = lo; i < hi; i++) s += deg[i];
    sh[t] = s;
    __syncthreads();
    for (int off = 1; off < 1024; off <<= 1) {
        int v = sh[t];
        int u = (t >= off) ? sh[t - off] : 0;
        __syncthreads();
        sh[t] = v + u;
        __syncthreads();
    }
    int run = (t == 0) ? 0 : sh[t - 1];
    for (int i = lo; i < hi; i++) {
        ptrArr[i] = run; cur[i] = run;
        if ((i & 511) == 0) bcur[i >> 9] = run;
        run += deg[i];
    }
    if (t == 1023) ptrArr[n] = sh[1023];
}

// phase 1: partition edges into dst-buckets of 512; packed record (dstLow9<<16)|src16
__global__ __launch_bounds__(256) void k_part(const int* __restrict__ src,
                                              const int* __restrict__ dst, int E,
                                              int* __restrict__ bcur,
                                              u32* __restrict__ part) {
    __shared__ int lh[NB];
    __shared__ int gb[NB];
    int tid = threadIdx.x;
    int base = blockIdx.x * 2048;
    for (int i = tid; i < NB; i += 256) lh[i] = 0;
    __syncthreads();
    int cnt = min(2048, E - base);
    int bkt[8], rank[8]; u32 pk[8];
    #pragma unroll
    for (int k = 0; k < 8; k++) {
        int i = tid + k * 256;
        if (i < cnt) {
            int s = src[base + i], d = dst[base + i];
            int b = d >> 9;
            bkt[k] = b;
            pk[k] = ((u32)(d & 511) << 16) | (u32)s;
            rank[k] = atomicAdd(&lh[b], 1);
        } else bkt[k] = -1;
    }
    __syncthreads();
    for (int i = tid; i < NB; i += 256) {
        int c = lh[i];
        gb[i] = c ? atomicAdd(&bcur[i], c) : 0;
    }
    __syncthreads();
    #pragma unroll
    for (int k = 0; k < 8; k++)
        if (bkt[k] >= 0) part[gb[bkt[k]] + rank[k]] = pk[k];
}

// phase 2: in-bucket scatter (cursor + store windows are L2-resident)
__global__ __launch_bounds__(256) void k_scat2(const u32* __restrict__ part,
                                               const int* __restrict__ ptrArr,
                                               int* __restrict__ cur,
                                               int* __restrict__ csr, int E, int n, int nb) {
    __shared__ int bb[NB + 1];
    int tid = threadIdx.x;
    for (int i = tid; i <= nb; i += 256) bb[i] = ptrArr[min(i << 9, n)];
    __syncthreads();
    int i = blockIdx.x * 256 + tid;
    if (i < E) {
        u32 pk = part[i];
        int lo = 0, hi = nb;                 // invariant: bb[lo] <= i < bb[hi]
        #pragma unroll
        for (int t = 0; t < 7; t++) {
            int mid = (lo + hi) >> 1;
            if (bb[mid] <= i) lo = mid; else hi = mid;
        }
        int d = (lo << 9) + (int)(pk >> 16);
        int pos = atomicAdd(&cur[d], 1);
        csr[pos] = (int)(pk & 0xffffu);
    }
}

// ---------------- weight prep (transposed bf16 B matrices) ----------------
__global__ void k_build_Bt1(const float* __restrict__ Ws, const float* __restrict__ Wd,
                            const float* __restrict__ Wd2, const float* __restrict__ as_,
                            const float* __restrict__ ad, const float* __restrict__ ad2,
                            u16* __restrict__ Bt) {
    int t = blockIdx.x * blockDim.x + threadIdx.x;
    if (t >= 144 * 512) return;
    int nn = t >> 9, k = t & 511;
    float v = 0.f;
    if (k < 500) {
        if (nn < 128) v = Ws[k * 128 + nn];
        else if (nn < 140) {
            int q = nn - 128; int h = q & 3;
            const float* W; const float* a;
            if (q < 4)      { W = Ws;  a = as_; }
            else if (q < 8) { W = Wd;  a = ad;  }
            else            { W = Wd2; a = ad2; }
            float s = 0.f;
            #pragma unroll 8
            for (int c = 0; c < 32; c++) s += W[k * 128 + h * 32 + c] * a[h * 32 + c];
            v = s;
        }
    }
    Bt[t] = f2bf(v);
}

__global__ void k_build_Bt2(const float* __restrict__ Ws, const float* __restrict__ Wd,
                            const float* __restrict__ Wd2, const float* __restrict__ as_,
                            const float* __restrict__ ad, const float* __restrict__ ad2,
                            u16* __restrict__ Bt) {
    int t = blockIdx.x * blockDim.x + threadIdx.x;
    if (t >= 48 * 256) return;
    int nn = t >> 8, k = t & 255;
    float v = 0.f;
    if (nn < 40) v = Ws[k * 40 + nn];
    else if (nn < 43) {
        const float* a = (nn == 40) ? as_ : (nn == 41) ? ad : ad2;
        const float* W = Ws;
        if (nn == 41) W = Wd; else if (nn == 42) W = Wd2;
        float s = 0.f;
        #pragma unroll 8
        for (int c = 0; c < 40; c++) s += W[k * 40 + c] * a[c];
        v = s;
    }
    Bt[t] = f2bf(v);
}

// ---------------- MFMA GEMM layer 1 ----------------
__global__ __launch_bounds__(256) void k_mgemm1(const float* __restrict__ A,
                                                const u16* __restrict__ Bt,
                                                u16* __restrict__ xb,
                                                float* __restrict__ alb, int M) {
    __shared__ __align__(16) u16 As[64][40];
    __shared__ __align__(16) u16 Bs[144][40];
    int tid = threadIdx.x;
    int wv = tid >> 6, lane = tid & 63;
    int l15 = lane & 15, k8 = lane >> 4;
    int rowBlk = blockIdx.x * 64;

    f32x4 acc[9];
    #pragma unroll
    for (int t = 0; t < 9; t++) acc[t] = (f32x4){0.f, 0.f, 0.f, 0.f};

    int r = tid >> 2, kc = (tid & 3) * 8;
    bool rowOK = (rowBlk + r) < M;
    const float* Ap0 = A + (size_t)(rowBlk + r) * 500;

    for (int k0 = 0; k0 < 512; k0 += 32) {
        float v[8];
        const float* Ap = Ap0 + k0 + kc;
        if (rowOK && (k0 + kc + 8 <= 500)) {
            float4 p0 = *(const float4*)Ap;
            float4 p1 = *(const float4*)(Ap + 4);
            v[0] = p0.x; v[1] = p0.y; v[2] = p0.z; v[3] = p0.w;
            v[4] = p1.x; v[5] = p1.y; v[6] = p1.z; v[7] = p1.w;
        } else {
            #pragma unroll
            for (int i = 0; i < 8; i++) {
                int gk = k0 + kc + i;
                v[i] = (rowOK && gk < 500) ? Ap[i] : 0.f;
            }
        }
        uint4 pk;
        pk.x = (u32)f2bf(v[0]) | ((u32)f2bf(v[1]) << 16);
        pk.y = (u32)f2bf(v[2]) | ((u32)f2bf(v[3]) << 16);
        pk.z = (u32)f2bf(v[4]) | ((u32)f2bf(v[5]) << 16);
        pk.w = (u32)f2bf(v[6]) | ((u32)f2bf(v[7]) << 16);
        *(uint4*)&As[r][kc] = pk;
        for (int idx = tid; idx < 144 * 4; idx += 256) {
            int nn = idx >> 2, c = (idx & 3) * 8;
            *(uint4*)&Bs[nn][c] = *(const uint4*)&Bt[nn * 512 + k0 + c];
        }
        __syncthreads();
        short8 af = *(const short8*)&As[wv * 16 + l15][k8 * 8];
        #pragma unroll
        for (int t = 0; t < 9; t++) {
            short8 bf = *(const short8*)&Bs[t * 16 + l15][k8 * 8];
            acc[t] = __builtin_amdgcn_mfma_f32_16x16x32_bf16(af, bf, acc[t], 0, 0, 0);
        }
        __syncthreads();
    }
    #pragma unroll
    for (int t = 0; t < 9; t++) {
        #pragma unroll
        for (int rr = 0; rr < 4; rr++) {
            int grow = rowBlk + wv * 16 + k8 * 4 + rr;
            if (grow < M) {
                if (t < 8) {
                    xb[(size_t)grow * 128 + t * 16 + l15] = f2bf(acc[t][rr]);
                } else if (l15 < 12) {
                    alb[(size_t)grow * 16 + l15] = acc[t][rr];
                }
            }
        }
    }
}

// ---------------- MFMA GEMM layer 2 ----------------
__global__ __launch_bounds__(256) void k_mgemm2(const u16* __restrict__ A,
                                                const u16* __restrict__ Bt,
                                                u16* __restrict__ xb,
                                                float* __restrict__ alb, int M) {
    __shared__ __align__(16) u16 As[64][40];
    __shared__ __align__(16) u16 Bs[48][40];
    int tid = threadIdx.x;
    int wv = tid >> 6, lane = tid & 63;
    int l15 = lane & 15, k8 = lane >> 4;
    int rowBlk = blockIdx.x * 64;

    f32x4 acc[3];
    #pragma unroll
    for (int t = 0; t < 3; t++) acc[t] = (f32x4){0.f, 0.f, 0.f, 0.f};

    int r = tid >> 2, kc = (tid & 3) * 8;
    bool rowOK = (rowBlk + r) < M;
    const u16* Ap0 = A + (size_t)(rowBlk + r) * 256;

    for (int k0 = 0; k0 < 256; k0 += 32) {
        uint4 pk = {0, 0, 0, 0};
        if (rowOK) pk = *(const uint4*)(Ap0 + k0 + kc);
        *(uint4*)&As[r][kc] = pk;
        if (tid < 48 * 4) {
            int nn = tid >> 2, c = (tid & 3) * 8;
            *(uint4*)&Bs[nn][c] = *(const uint4*)&Bt[nn * 256 + k0 + c];
        }
        __syncthreads();
        short8 af = *(const short8*)&As[wv * 16 + l15][k8 * 8];
        #pragma unroll
        for (int t = 0; t < 3; t++) {
            short8 bf = *(const short8*)&Bs[t * 16 + l15][k8 * 8];
            acc[t] = __builtin_amdgcn_mfma_f32_16x16x32_bf16(af, bf, acc[t], 0, 0, 0);
        }
        __syncthreads();
    }
    #pragma unroll
    for (int t = 0; t < 3; t++) {
        #pragma unroll
        for (int rr = 0; rr < 4; rr++) {
            int grow = rowBlk + wv * 16 + k8 * 4 + rr;
            if (grow < M) {
                int col = t * 16 + l15;
                if (col < 40) xb[(size_t)grow * 40 + col] = f2bf(acc[t][rr]);
                else if (col < 43) alb[(size_t)grow * 4 + (col - 40)] = acc[t][rr];
            }
        }
    }
}

// ---------------- layer-1 propagate ----------------
__global__ __launch_bounds__(256) void k_prop1(const int* __restrict__ ptr, const int* __restrict__ csr,
                                               const float* __restrict__ al, int doff,
                                               const uint2* __restrict__ xbv,
                                               u16* __restrict__ out, int n) {
    __shared__ int sbuf[4][64];
    __shared__ __align__(16) float wbuf[4][64][4];
    int tid = threadIdx.x;
    int wv = tid >> 6, lane = tid & 63;
    int wid = (blockIdx.x * 256 + tid) >> 6;
    if (wid >= n) return;
    int b = ptr[wid], e = ptr[wid + 1];
    float4 adv = *(const float4*)(al + (size_t)wid * 16 + doff);
    int l5 = lane & 31, h2 = l5 >> 3, half = lane >> 5;

    float acc0 = 0.f, acc1 = 0.f, acc2 = 0.f, acc3 = 0.f;
    float dn0 = 0.f, dn1 = 0.f, dn2 = 0.f, dn3 = 0.f;

    for (int cb = b; cb < e; cb += 64) {
        int cnt = min(64, e - cb);
        int s = 0;
        float w0 = 0.f, w1 = 0.f, w2 = 0.f, w3 = 0.f;
        if (lane < cnt) {
            s = csr[cb + lane];
            float4 av = *(const float4*)(al + (size_t)s * 16);
            float a0 = av.x + adv.x; a0 = a0 > 0.f ? a0 : 0.2f * a0; w0 = __expf(a0);
            float a1 = av.y + adv.y; a1 = a1 > 0.f ? a1 : 0.2f * a1; w1 = __expf(a1);
            float a2 = av.z + adv.z; a2 = a2 > 0.f ? a2 : 0.2f * a2; w2 = __expf(a2);
            float a3 = av.w + adv.w; a3 = a3 > 0.f ? a3 : 0.2f * a3; w3 = __expf(a3);
        }
        dn0 += w0; dn1 += w1; dn2 += w2; dn3 += w3;
        sbuf[wv][lane] = s;
        float4 wq; wq.x = w0; wq.y = w1; wq.z = w2; wq.w = w3;
        *(float4*)&wbuf[wv][lane][0] = wq;
        #pragma unroll 4
        for (int j = 0; j < cnt; j += 2) {
            int jj = j + half;
            int sj = sbuf[wv][jj];
            float wj = wbuf[wv][jj][h2];
            uint2 pk = xbv[(size_t)sj * 32 + l5];
            acc0 = fmaf(wj, bl(pk.x), acc0);
            acc1 = fmaf(wj, bh(pk.x), acc1);
            acc2 = fmaf(wj, bl(pk.y), acc2);
            acc3 = fmaf(wj, bh(pk.y), acc3);
        }
    }
    acc0 += __shfl_xor(acc0, 32);
    acc1 += __shfl_xor(acc1, 32);
    acc2 += __shfl_xor(acc2, 32);
    acc3 += __shfl_xor(acc3, 32);
    #pragma unroll
    for (int o = 32; o > 0; o >>= 1) {
        dn0 += __shfl_xor(dn0, o);
        dn1 += __shfl_xor(dn1, o);
        dn2 += __shfl_xor(dn2, o);
        dn3 += __shfl_xor(dn3, o);
    }
    float dh = (h2 == 0) ? dn0 : (h2 == 1) ? dn1 : (h2 == 2) ? dn2 : dn3;
    float inv = 1.f / (dh + 1e-16f);
    float r0 = acc0 * inv, r1 = acc1 * inv, r2 = acc2 * inv, r3 = acc3 * inv;
    r0 = r0 > 0.f ? r0 : __expf(r0) - 1.f;
    r1 = r1 > 0.f ? r1 : __expf(r1) - 1.f;
    r2 = r2 > 0.f ? r2 : __expf(r2) - 1.f;
    r3 = r3 > 0.f ? r3 : __expf(r3) - 1.f;
    if (half == 0) {
        uint2 st;
        st.x = (u32)f2bf(r0) | ((u32)f2bf(r1) << 16);
        st.y = (u32)f2bf(r2) | ((u32)f2bf(r3) << 16);
        *(uint2*)(out + (size_t)wid * 256 + 4 * l5) = st;
    }
}

// ---------------- layer-2 propagate ----------------
__global__ __launch_bounds__(256) void k_prop2(const int* __restrict__ ptr, const int* __restrict__ csr,
                                               const float* __restrict__ al, int didx,
                                               const uint2* __restrict__ xbv,
                                               float* __restrict__ out, int n) {
    __shared__ int2 swb[4][64];
    int tid = threadIdx.x;
    int wv = tid >> 6, lane = tid & 63;
    int wid = (blockIdx.x * 256 + tid) >> 6;
    if (wid >= n) return;
    int b = ptr[wid], e = ptr[wid + 1];
    float ad = al[(size_t)wid * 4 + didx];
    int g = lane / 10;
    int cp = lane - g * 10;
    bool act = g < 6;

    float acc0 = 0.f, acc1 = 0.f, acc2 = 0.f, acc3 = 0.f;
    float den = 0.f;

    for (int cb = b; cb < e; cb += 64) {
        int cnt = min(64, e - cb);
        int s = 0; float w = 0.f;
        if (lane < cnt) {
            s = csr[cb + lane];
            float a = al[(size_t)s * 4] + ad;
            a = a > 0.f ? a : 0.2f * a;
            w = __expf(a);
        }
        den += w;
        swb[wv][lane] = make_int2(s, __float_as_int(w));
        #pragma unroll 2
        for (int j = 0; j < cnt; j += 6) {
            int jj = j + g;
            bool valid = act && (jj < cnt);
            int2 sw = swb[wv][valid ? jj : 0];
            float wj = valid ? __int_as_float(sw.y) : 0.f;
            uint2 pk = xbv[(size_t)sw.x * 10 + cp];
            acc0 = fmaf(wj, bl(pk.x), acc0);
            acc1 = fmaf(wj, bh(pk.x), acc1);
            acc2 = fmaf(wj, bl(pk.y), acc2);
            acc3 = fmaf(wj, bh(pk.y), acc3);
        }
    }
    float t0;
    t0 = acc0 + __shfl(acc0, (lane + 30) & 63); acc0 = t0 + __shfl(t0, (lane + 10) & 63) + __shfl(t0, (lane + 20) & 63);
    t0 = acc1 + __shfl(acc1, (lane + 30) & 63); acc1 = t0 + __shfl(t0, (lane + 10) & 63) + __shfl(t0, (lane + 20) & 63);
    t0 = acc2 + __shfl(acc2, (lane + 30) & 63); acc2 = t0 + __shfl(t0, (lane + 10) & 63) + __shfl(t0, (lane + 20) & 63);
    t0 = acc3 + __shfl(acc3, (lane + 30) & 63); acc3 = t0 + __shfl(t0, (lane + 10) & 63) + __shfl(t0, (lane + 20) & 63);
    #pragma unroll
    for (int o = 32; o > 0; o >>= 1) den += __shfl_xor(den, o);
    if (lane < 10) {
        float inv = 1.f / (den + 1e-16f);
        float4 st; st.x = acc0 * inv; st.y = acc1 * inv; st.z = acc2 * inv; st.w = acc3 * inv;
        *(float4*)(out + (size_t)wid * 80 + 4 * cp) = st;
    }
}

// ---------------- log_softmax ----------------
__global__ __launch_bounds__(256) void k_lsm(const float* __restrict__ h2, float* __restrict__ out, int n) {
    int wid = (blockIdx.x * blockDim.x + threadIdx.x) >> 6;
    int lane = threadIdx.x & 63;
    if (wid >= n) return;
    const float* row = h2 + (size_t)wid * 80;
    float v0 = row[lane];
    float v1 = (lane < 16) ? row[64 + lane] : -INFINITY;
    float m = fmaxf(v0, v1);
    for (int o = 32; o > 0; o >>= 1) m = fmaxf(m, __shfl_xor(m, o));
    float s = __expf(v0 - m) + ((lane < 16) ? __expf(v1 - m) : 0.f);
    for (int o = 32; o > 0; o >>= 1) s += __shfl_xor(s, o);
    float ls = m + logf(s);
    out[(size_t)wid * 80 + lane] = v0 - ls;
    if (lane < 16) out[(size_t)wid * 80 + 64 + lane] = v1 - ls;
}

// ---------------- launch ----------------

extern "C" void kernel_launch(void* const* d_in, const int* in_sizes, int n_in,
                              void* d_out, int out_size, void* d_ws, size_t ws_size,
                              hipStream_t stream) {
    const float* x       = (const float*)d_in[0];
    const int*   e1      = (const int*)d_in[1];
    const int*   e2      = (const int*)d_in[2];
    const float* W_src1  = (const float*)d_in[3];
    const float* W_dst1  = (const float*)d_in[4];
    const float* W_dst21 = (const float*)d_in[5];
    const float* a_src1  = (const float*)d_in[6];
    const float* a_dst1  = (const float*)d_in[7];
    const float* a_dst21 = (const float*)d_in[8];
    const float* W_src2  = (const float*)d_in[9];
    const float* W_dst2  = (const float*)d_in[10];
    const float* W_dst22 = (const float*)d_in[11];
    const float* a_src2  = (const float*)d_in[12];
    const float* a_dst2  = (const float*)d_in[13];
    const float* a_dst22 = (const float*)d_in[14];
    float* out = (float*)d_out;

    const int FIN = 500;
    int n  = in_sizes[0] / FIN;     // 50000
    int E1 = in_sizes[1] / 2;       // 300000
    int E2 = in_sizes[2] / 2;       // ~1.7M
    const int* src1 = e1, *dst1 = e1 + E1;
    const int* src2 = e2, *dst2 = e2 + E2;
    int nb = (n + 511) >> 9;        // 98

    char* w = (char*)d_ws;
    auto alloc = [&](size_t bytes) -> char* {
        char* p = w; w += (bytes + 255) & ~(size_t)255; return p;
    };
    u16*   xb1  = (u16*)alloc((size_t)n * 128 * 2);   // layer1 feats bf16 [n][128]
    float* alb1 = (float*)alloc((size_t)n * 16 * 4);  // [als(4)|ald1(4)|ald21(4)|pad]
    u16*   hbuf = (u16*)alloc((size_t)n * 256 * 2);   // elu(concat) hidden bf16 [n][256]
    u16*   xb2  = (u16*)alloc((size_t)n * 40 * 2);    // layer2 feats bf16 [n][40]
    float* alb2 = (float*)alloc((size_t)n * 4 * 4);   // [als|ald1|ald22|pad]
    float* h2   = (float*)alloc((size_t)n * 80 * 4);  // pre-logsoftmax fp32
    u16*   Bt1  = (u16*)alloc(144 * 512 * 2);
    u16*   Bt2  = (u16*)alloc(48 * 256 * 2);
    int* ptr1 = (int*)alloc((size_t)(n + 1) * 4);
    int* cur1 = (int*)alloc((size_t)n * 4);
    int* deg1 = (int*)alloc((size_t)n * 4);
    int* csr1 = (int*)alloc((size_t)E1 * 4);
    int* ptr2 = (int*)alloc((size_t)(n + 1) * 4);
    int* cur2 = (int*)alloc((size_t)n * 4);
    int* deg2 = (int*)alloc((size_t)n * 4);
    int* csr2 = (int*)alloc((size_t)E2 * 4);
    int* bcur1 = (int*)alloc((NB + 1) * 4);
    int* bcur2 = (int*)alloc((NB + 1) * 4);
    // partition scratch aliases h2 (dead until k_prop2; stream-ordered)
    u32* part2 = (u32*)h2;
    u32* part1 = part2 + E2;

    // CSR build
    hipMemsetAsync(deg1, 0, (size_t)n * 4, stream);
    hipMemsetAsync(deg2, 0, (size_t)n * 4, stream);
    k_hist<<<(E1 + 255) / 256, 256, 0, stream>>>(deg1, dst1, E1);
    k_hist<<<(E2 + 255) / 256, 256, 0, stream>>>(deg2, dst2, E2);
    k_scan<<<1, 1024, 0, stream>>>(deg1, ptr1, cur1, bcur1, n);
    k_scan<<<1, 1024, 0, stream>>>(deg2, ptr2, cur2, bcur2, n);
    k_part<<<(E1 + 2047) / 2048, 256, 0, stream>>>(src1, dst1, E1, bcur1, part1);
    k_part<<<(E2 + 2047) / 2048, 256, 0, stream>>>(src2, dst2, E2, bcur2, part2);
    k_scat2<<<(E1 + 255) / 256, 256, 0, stream>>>(part1, ptr1, cur1, csr1, E1, n, nb);
    k_scat2<<<(E2 + 255) / 256, 256, 0, stream>>>(part2, ptr2, cur2, csr2, E2, n, nb);

    // layer 1: fused MFMA GEMM (features + attention-logit projections)
    k_build_Bt1<<<(144 * 512 + 255) / 256, 256, 0, stream>>>(W_src1, W_dst1, W_dst21,
                                                             a_src1, a_dst1, a_dst21, Bt1);
    k_mgemm1<<<(n + 63) / 64, 256, 0, stream>>>(x, Bt1, xb1, alb1, n);

    // layer 1 propagate (+ fused ELU), bf16 hidden out
    int pblocks = (n + 3) / 4;
    k_prop1<<<pblocks, 256, 0, stream>>>(ptr1, csr1, alb1, 4, (const uint2*)xb1, hbuf + 0, n);
    k_prop1<<<pblocks, 256, 0, stream>>>(ptr2, csr2, alb1, 8, (const uint2*)xb1, hbuf + 128, n);

    // layer 2: MFMA GEMM on bf16 hidden
    k_build_Bt2<<<(48 * 256 + 255) / 256, 256, 0, stream>>>(W_src2, W_dst2, W_dst22,
                                                            a_src2, a_dst2, a_dst22, Bt2);
    k_mgemm2<<<(n + 63) / 64, 256, 0, stream>>>(hbuf, Bt2, xb2, alb2, n);

    // layer 2 propagate
    k_prop2<<<pblocks, 256, 0, stream>>>(ptr1, csr1, alb2, 1, (const uint2*)xb2, h2 + 0, n);
    k_prop2<<<pblocks, 256, 0, stream>>>(ptr2, csr2, alb2, 2, (const uint2*)xb2, h2 + 40, n);

    // log_softmax
    k_lsm<<<pblocks, 256, 0, stream>>>(h2, out, n);
}

// Round 5
// 401.668 us; speedup vs baseline: 3.0594x; 1.4792x over previous
//
#include <hip/hip_runtime.h>
#include <hip/hip_bf16.h>
#include <math.h>

typedef unsigned short u16;
typedef unsigned int u32;
typedef __attribute__((ext_vector_type(8))) short short8;
typedef __attribute__((ext_vector_type(4))) float f32x4;

#define NB 128  // bucket slots (actual buckets = ceil(n/512) = 98 for n=50000)

static __device__ __forceinline__ u16 f2bf(float f) {
    u32 u = __float_as_uint(f);
    u32 r = (u + 0x7fffu + ((u >> 16) & 1u)) >> 16;
    return (u16)r;
}
static __device__ __forceinline__ float bl(u32 u) { return __uint_as_float(u << 16); }
static __device__ __forceinline__ float bh(u32 u) { return __uint_as_float(u & 0xffff0000u); }

// ---------------- CSR build ----------------

__global__ void k_hist(int* __restrict__ deg, const int* __restrict__ dst, int E) {
    int i = blockIdx.x * blockDim.x + threadIdx.x;
    if (i < E) atomicAdd(&deg[dst[i]], 1);
}

// ---- multi-block exclusive scan: deg[0..n) -> ptr/cur/bcur, ptr[n] ----
// phase A: per-block (2048 elems) partial sums
__global__ __launch_bounds__(256) void k_scan_a(const int* __restrict__ deg,
                                                int* __restrict__ bsum, int n) {
    __shared__ int sh[256];
    int t = threadIdx.x;
    int base = blockIdx.x * 2048 + t * 8;
    int s = 0;
    #pragma unroll
    for (int k = 0; k < 8; k++) { int i = base + k; if (i < n) s += deg[i]; }
    sh[t] = s;
    __syncthreads();
    for (int off = 128; off > 0; off >>= 1) {
        if (t < off) sh[t] += sh[t + off];
        __syncthreads();
    }
    if (t == 0) bsum[blockIdx.x] = sh[0];
}

// phase B: exclusive scan of block sums (nbk <= 64), writes total to ptrN
__global__ void k_scan_b(int* __restrict__ bsum, int* __restrict__ ptrN, int nbk) {
    int t = threadIdx.x;  // 64 threads
    int v = (t < nbk) ? bsum[t] : 0;
    int inc = v;
    #pragma unroll
    for (int off = 1; off < 64; off <<= 1) {
        int u = __shfl_up(inc, off);
        if (t >= off) inc += u;
    }
    if (t < nbk) bsum[t] = inc - v;
    if (t == 63) *ptrN = inc;
}

// phase C: full exclusive scan write-out (ptr, cur, bucket bases)
__global__ __launch_bounds__(256) void k_scan_c(const int* __restrict__ deg,
                                                const int* __restrict__ bsum,
                                                int* __restrict__ ptrArr, int* __restrict__ cur,
                                                int* __restrict__ bcur, int n) {
    __shared__ int sh[256];
    int t = threadIdx.x;
    int base = blockIdx.x * 2048 + t * 8;
    int v[8]; int s = 0;
    #pragma unroll
    for (int k = 0; k < 8; k++) {
        int i = base + k;
        v[k] = (i < n) ? deg[i] : 0;
        s += v[k];
    }
    sh[t] = s;
    __syncthreads();
    for (int off = 1; off < 256; off <<= 1) {
        int val = sh[t];
        int add = (t >= off) ? sh[t - off] : 0;
        __syncthreads();
        sh[t] = val + add;
        __syncthreads();
    }
    int run = bsum[blockIdx.x] + ((t == 0) ? 0 : sh[t - 1]);
    #pragma unroll
    for (int k = 0; k < 8; k++) {
        int i = base + k;
        if (i < n) {
            ptrArr[i] = run; cur[i] = run;
            if ((i & 511) == 0) bcur[i >> 9] = run;
            run += v[k];
        }
    }
}

// phase 1: partition edges into dst-buckets of 512; packed record (dstLow9<<16)|src16
__global__ __launch_bounds__(256) void k_part(const int* __restrict__ src,
                                              const int* __restrict__ dst, int E,
                                              int* __restrict__ bcur,
                                              u32* __restrict__ part) {
    __shared__ int lh[NB];
    __shared__ int gb[NB];
    int tid = threadIdx.x;
    int base = blockIdx.x * 2048;
    for (int i = tid; i < NB; i += 256) lh[i] = 0;
    __syncthreads();
    int cnt = min(2048, E - base);
    int bkt[8], rank[8]; u32 pk[8];
    #pragma unroll
    for (int k = 0; k < 8; k++) {
        int i = tid + k * 256;
        if (i < cnt) {
            int s = src[base + i], d = dst[base + i];
            int b = d >> 9;
            bkt[k] = b;
            pk[k] = ((u32)(d & 511) << 16) | (u32)s;
            rank[k] = atomicAdd(&lh[b], 1);
        } else bkt[k] = -1;
    }
    __syncthreads();
    for (int i = tid; i < NB; i += 256) {
        int c = lh[i];
        gb[i] = c ? atomicAdd(&bcur[i], c) : 0;
    }
    __syncthreads();
    #pragma unroll
    for (int k = 0; k < 8; k++)
        if (bkt[k] >= 0) part[gb[bkt[k]] + rank[k]] = pk[k];
}

// phase 2: in-bucket scatter (cursor + store windows are L2-resident)
__global__ __launch_bounds__(256) void k_scat2(const u32* __restrict__ part,
                                               const int* __restrict__ ptrArr,
                                               int* __restrict__ cur,
                                               int* __restrict__ csr, int E, int n, int nb) {
    __shared__ int bb[NB + 1];
    int tid = threadIdx.x;
    for (int i = tid; i <= nb; i += 256) bb[i] = ptrArr[min(i << 9, n)];
    __syncthreads();
    int i = blockIdx.x * 256 + tid;
    if (i < E) {
        u32 pk = part[i];
        int lo = 0, hi = nb;
        #pragma unroll
        for (int t = 0; t < 7; t++) {
            int mid = (lo + hi) >> 1;
            if (bb[mid] <= i) lo = mid; else hi = mid;
        }
        int d = (lo << 9) + (int)(pk >> 16);
        int pos = atomicAdd(&cur[d], 1);
        csr[pos] = (int)(pk & 0xffffu);
    }
}

// ---------------- weight prep (transposed bf16 B matrices) ----------------
__global__ void k_build_Bt1(const float* __restrict__ Ws, const float* __restrict__ Wd,
                            const float* __restrict__ Wd2, const float* __restrict__ as_,
                            const float* __restrict__ ad, const float* __restrict__ ad2,
                            u16* __restrict__ Bt) {
    int t = blockIdx.x * blockDim.x + threadIdx.x;
    if (t >= 144 * 512) return;
    int nn = t >> 9, k = t & 511;
    float v = 0.f;
    if (k < 500) {
        if (nn < 128) v = Ws[k * 128 + nn];
        else if (nn < 140) {
            int q = nn - 128; int h = q & 3;
            const float* W; const float* a;
            if (q < 4)      { W = Ws;  a = as_; }
            else if (q < 8) { W = Wd;  a = ad;  }
            else            { W = Wd2; a = ad2; }
            float s = 0.f;
            #pragma unroll 8
            for (int c = 0; c < 32; c++) s += W[k * 128 + h * 32 + c] * a[h * 32 + c];
            v = s;
        }
    }
    Bt[t] = f2bf(v);
}

__global__ void k_build_Bt2(const float* __restrict__ Ws, const float* __restrict__ Wd,
                            const float* __restrict__ Wd2, const float* __restrict__ as_,
                            const float* __restrict__ ad, const float* __restrict__ ad2,
                            u16* __restrict__ Bt) {
    int t = blockIdx.x * blockDim.x + threadIdx.x;
    if (t >= 48 * 256) return;
    int nn = t >> 8, k = t & 255;
    float v = 0.f;
    if (nn < 40) v = Ws[k * 40 + nn];
    else if (nn < 43) {
        const float* a = (nn == 40) ? as_ : (nn == 41) ? ad : ad2;
        const float* W = Ws;
        if (nn == 41) W = Wd; else if (nn == 42) W = Wd2;
        float s = 0.f;
        #pragma unroll 8
        for (int c = 0; c < 40; c++) s += W[k * 40 + c] * a[c];
        v = s;
    }
    Bt[t] = f2bf(v);
}

// ---------------- MFMA GEMM layer 1 ----------------
__global__ __launch_bounds__(256) void k_mgemm1(const float* __restrict__ A,
                                                const u16* __restrict__ Bt,
                                                u16* __restrict__ xb,
                                                float* __restrict__ alb, int M) {
    __shared__ __align__(16) u16 As[64][40];
    __shared__ __align__(16) u16 Bs[144][40];
    int tid = threadIdx.x;
    int wv = tid >> 6, lane = tid & 63;
    int l15 = lane & 15, k8 = lane >> 4;
    int rowBlk = blockIdx.x * 64;

    f32x4 acc[9];
    #pragma unroll
    for (int t = 0; t < 9; t++) acc[t] = (f32x4){0.f, 0.f, 0.f, 0.f};

    int r = tid >> 2, kc = (tid & 3) * 8;
    bool rowOK = (rowBlk + r) < M;
    const float* Ap0 = A + (size_t)(rowBlk + r) * 500;

    for (int k0 = 0; k0 < 512; k0 += 32) {
        float v[8];
        const float* Ap = Ap0 + k0 + kc;
        if (rowOK && (k0 + kc + 8 <= 500)) {
            float4 p0 = *(const float4*)Ap;
            float4 p1 = *(const float4*)(Ap + 4);
            v[0] = p0.x; v[1] = p0.y; v[2] = p0.z; v[3] = p0.w;
            v[4] = p1.x; v[5] = p1.y; v[6] = p1.z; v[7] = p1.w;
        } else {
            #pragma unroll
            for (int i = 0; i < 8; i++) {
                int gk = k0 + kc + i;
                v[i] = (rowOK && gk < 500) ? Ap[i] : 0.f;
            }
        }
        uint4 pk;
        pk.x = (u32)f2bf(v[0]) | ((u32)f2bf(v[1]) << 16);
        pk.y = (u32)f2bf(v[2]) | ((u32)f2bf(v[3]) << 16);
        pk.z = (u32)f2bf(v[4]) | ((u32)f2bf(v[5]) << 16);
        pk.w = (u32)f2bf(v[6]) | ((u32)f2bf(v[7]) << 16);
        *(uint4*)&As[r][kc] = pk;
        for (int idx = tid; idx < 144 * 4; idx += 256) {
            int nn = idx >> 2, c = (idx & 3) * 8;
            *(uint4*)&Bs[nn][c] = *(const uint4*)&Bt[nn * 512 + k0 + c];
        }
        __syncthreads();
        short8 af = *(const short8*)&As[wv * 16 + l15][k8 * 8];
        #pragma unroll
        for (int t = 0; t < 9; t++) {
            short8 bf = *(const short8*)&Bs[t * 16 + l15][k8 * 8];
            acc[t] = __builtin_amdgcn_mfma_f32_16x16x32_bf16(af, bf, acc[t], 0, 0, 0);
        }
        __syncthreads();
    }
    #pragma unroll
    for (int t = 0; t < 9; t++) {
        #pragma unroll
        for (int rr = 0; rr < 4; rr++) {
            int grow = rowBlk + wv * 16 + k8 * 4 + rr;
            if (grow < M) {
                if (t < 8) {
                    xb[(size_t)grow * 128 + t * 16 + l15] = f2bf(acc[t][rr]);
                } else if (l15 < 12) {
                    alb[(size_t)grow * 16 + l15] = acc[t][rr];
                }
            }
        }
    }
}

// ---------------- MFMA GEMM layer 2 ----------------
__global__ __launch_bounds__(256) void k_mgemm2(const u16* __restrict__ A,
                                                const u16* __restrict__ Bt,
                                                u16* __restrict__ xb,
                                                float* __restrict__ alb, int M) {
    __shared__ __align__(16) u16 As[64][40];
    __shared__ __align__(16) u16 Bs[48][40];
    int tid = threadIdx.x;
    int wv = tid >> 6, lane = tid & 63;
    int l15 = lane & 15, k8 = lane >> 4;
    int rowBlk = blockIdx.x * 64;

    f32x4 acc[3];
    #pragma unroll
    for (int t = 0; t < 3; t++) acc[t] = (f32x4){0.f, 0.f, 0.f, 0.f};

    int r = tid >> 2, kc = (tid & 3) * 8;
    bool rowOK = (rowBlk + r) < M;
    const u16* Ap0 = A + (size_t)(rowBlk + r) * 256;

    for (int k0 = 0; k0 < 256; k0 += 32) {
        uint4 pk = {0, 0, 0, 0};
        if (rowOK) pk = *(const uint4*)(Ap0 + k0 + kc);
        *(uint4*)&As[r][kc] = pk;
        if (tid < 48 * 4) {
            int nn = tid >> 2, c = (tid & 3) * 8;
            *(uint4*)&Bs[nn][c] = *(const uint4*)&Bt[nn * 256 + k0 + c];
        }
        __syncthreads();
        short8 af = *(const short8*)&As[wv * 16 + l15][k8 * 8];
        #pragma unroll
        for (int t = 0; t < 3; t++) {
            short8 bf = *(const short8*)&Bs[t * 16 + l15][k8 * 8];
            acc[t] = __builtin_amdgcn_mfma_f32_16x16x32_bf16(af, bf, acc[t], 0, 0, 0);
        }
        __syncthreads();
    }
    #pragma unroll
    for (int t = 0; t < 3; t++) {
        #pragma unroll
        for (int rr = 0; rr < 4; rr++) {
            int grow = rowBlk + wv * 16 + k8 * 4 + rr;
            if (grow < M) {
                int col = t * 16 + l15;
                if (col < 40) xb[(size_t)grow * 40 + col] = f2bf(acc[t][rr]);
                else if (col < 43) alb[(size_t)grow * 4 + (col - 40)] = acc[t][rr];
            }
        }
    }
}

// ---------------- layer-1 propagate ----------------
__global__ __launch_bounds__(256) void k_prop1(const int* __restrict__ ptr, const int* __restrict__ csr,
                                               const float* __restrict__ al, int doff,
                                               const uint2* __restrict__ xbv,
                                               u16* __restrict__ out, int n) {
    __shared__ int sbuf[4][64];
    __shared__ __align__(16) float wbuf[4][64][4];
    int tid = threadIdx.x;
    int wv = tid >> 6, lane = tid & 63;
    int wid = (blockIdx.x * 256 + tid) >> 6;
    if (wid >= n) return;
    int b = ptr[wid], e = ptr[wid + 1];
    float4 adv = *(const float4*)(al + (size_t)wid * 16 + doff);
    int l5 = lane & 31, h2 = l5 >> 3, half = lane >> 5;

    float acc0 = 0.f, acc1 = 0.f, acc2 = 0.f, acc3 = 0.f;
    float dn0 = 0.f, dn1 = 0.f, dn2 = 0.f, dn3 = 0.f;

    for (int cb = b; cb < e; cb += 64) {
        int cnt = min(64, e - cb);
        int s = 0;
        float w0 = 0.f, w1 = 0.f, w2 = 0.f, w3 = 0.f;
        if (lane < cnt) {
            s = csr[cb + lane];
            float4 av = *(const float4*)(al + (size_t)s * 16);
            float a0 = av.x + adv.x; a0 = a0 > 0.f ? a0 : 0.2f * a0; w0 = __expf(a0);
            float a1 = av.y + adv.y; a1 = a1 > 0.f ? a1 : 0.2f * a1; w1 = __expf(a1);
            float a2 = av.z + adv.z; a2 = a2 > 0.f ? a2 : 0.2f * a2; w2 = __expf(a2);
            float a3 = av.w + adv.w; a3 = a3 > 0.f ? a3 : 0.2f * a3; w3 = __expf(a3);
        }
        dn0 += w0; dn1 += w1; dn2 += w2; dn3 += w3;
        sbuf[wv][lane] = s;
        float4 wq; wq.x = w0; wq.y = w1; wq.z = w2; wq.w = w3;
        *(float4*)&wbuf[wv][lane][0] = wq;
        #pragma unroll 4
        for (int j = 0; j < cnt; j += 2) {
            int jj = j + half;
            int sj = sbuf[wv][jj];
            float wj = wbuf[wv][jj][h2];
            uint2 pk = xbv[(size_t)sj * 32 + l5];
            acc0 = fmaf(wj, bl(pk.x), acc0);
            acc1 = fmaf(wj, bh(pk.x), acc1);
            acc2 = fmaf(wj, bl(pk.y), acc2);
            acc3 = fmaf(wj, bh(pk.y), acc3);
        }
    }
    acc0 += __shfl_xor(acc0, 32);
    acc1 += __shfl_xor(acc1, 32);
    acc2 += __shfl_xor(acc2, 32);
    acc3 += __shfl_xor(acc3, 32);
    #pragma unroll
    for (int o = 32; o > 0; o >>= 1) {
        dn0 += __shfl_xor(dn0, o);
        dn1 += __shfl_xor(dn1, o);
        dn2 += __shfl_xor(dn2, o);
        dn3 += __shfl_xor(dn3, o);
    }
    float dh = (h2 == 0) ? dn0 : (h2 == 1) ? dn1 : (h2 == 2) ? dn2 : dn3;
    float inv = 1.f / (dh + 1e-16f);
    float r0 = acc0 * inv, r1 = acc1 * inv, r2 = acc2 * inv, r3 = acc3 * inv;
    r0 = r0 > 0.f ? r0 : __expf(r0) - 1.f;
    r1 = r1 > 0.f ? r1 : __expf(r1) - 1.f;
    r2 = r2 > 0.f ? r2 : __expf(r2) - 1.f;
    r3 = r3 > 0.f ? r3 : __expf(r3) - 1.f;
    if (half == 0) {
        uint2 st;
        st.x = (u32)f2bf(r0) | ((u32)f2bf(r1) << 16);
        st.y = (u32)f2bf(r2) | ((u32)f2bf(r3) << 16);
        *(uint2*)(out + (size_t)wid * 256 + 4 * l5) = st;
    }
}

// ---------------- layer-2 propagate ----------------
__global__ __launch_bounds__(256) void k_prop2(const int* __restrict__ ptr, const int* __restrict__ csr,
                                               const float* __restrict__ al, int didx,
                                               const uint2* __restrict__ xbv,
                                               float* __restrict__ out, int n) {
    __shared__ int2 swb[4][64];
    int tid = threadIdx.x;
    int wv = tid >> 6, lane = tid & 63;
    int wid = (blockIdx.x * 256 + tid) >> 6;
    if (wid >= n) return;
    int b = ptr[wid], e = ptr[wid + 1];
    float ad = al[(size_t)wid * 4 + didx];
    int g = lane / 10;
    int cp = lane - g * 10;
    bool act = g < 6;

    float acc0 = 0.f, acc1 = 0.f, acc2 = 0.f, acc3 = 0.f;
    float den = 0.f;

    for (int cb = b; cb < e; cb += 64) {
        int cnt = min(64, e - cb);
        int s = 0; float w = 0.f;
        if (lane < cnt) {
            s = csr[cb + lane];
            float a = al[(size_t)s * 4] + ad;
            a = a > 0.f ? a : 0.2f * a;
            w = __expf(a);
        }
        den += w;
        swb[wv][lane] = make_int2(s, __float_as_int(w));
        #pragma unroll 2
        for (int j = 0; j < cnt; j += 6) {
            int jj = j + g;
            bool valid = act && (jj < cnt);
            int2 sw = swb[wv][valid ? jj : 0];
            float wj = valid ? __int_as_float(sw.y) : 0.f;
            uint2 pk = xbv[(size_t)sw.x * 10 + cp];
            acc0 = fmaf(wj, bl(pk.x), acc0);
            acc1 = fmaf(wj, bh(pk.x), acc1);
            acc2 = fmaf(wj, bl(pk.y), acc2);
            acc3 = fmaf(wj, bh(pk.y), acc3);
        }
    }
    float t0;
    t0 = acc0 + __shfl(acc0, (lane + 30) & 63); acc0 = t0 + __shfl(t0, (lane + 10) & 63) + __shfl(t0, (lane + 20) & 63);
    t0 = acc1 + __shfl(acc1, (lane + 30) & 63); acc1 = t0 + __shfl(t0, (lane + 10) & 63) + __shfl(t0, (lane + 20) & 63);
    t0 = acc2 + __shfl(acc2, (lane + 30) & 63); acc2 = t0 + __shfl(t0, (lane + 10) & 63) + __shfl(t0, (lane + 20) & 63);
    t0 = acc3 + __shfl(acc3, (lane + 30) & 63); acc3 = t0 + __shfl(t0, (lane + 10) & 63) + __shfl(t0, (lane + 20) & 63);
    #pragma unroll
    for (int o = 32; o > 0; o >>= 1) den += __shfl_xor(den, o);
    if (lane < 10) {
        float inv = 1.f / (den + 1e-16f);
        float4 st; st.x = acc0 * inv; st.y = acc1 * inv; st.z = acc2 * inv; st.w = acc3 * inv;
        *(float4*)(out + (size_t)wid * 80 + 4 * cp) = st;
    }
}

// ---------------- log_softmax ----------------
__global__ __launch_bounds__(256) void k_lsm(const float* __restrict__ h2, float* __restrict__ out, int n) {
    int wid = (blockIdx.x * blockDim.x + threadIdx.x) >> 6;
    int lane = threadIdx.x & 63;
    if (wid >= n) return;
    const float* row = h2 + (size_t)wid * 80;
    float v0 = row[lane];
    float v1 = (lane < 16) ? row[64 + lane] : -INFINITY;
    float m = fmaxf(v0, v1);
    for (int o = 32; o > 0; o >>= 1) m = fmaxf(m, __shfl_xor(m, o));
    float s = __expf(v0 - m) + ((lane < 16) ? __expf(v1 - m) : 0.f);
    for (int o = 32; o > 0; o >>= 1) s += __shfl_xor(s, o);
    float ls = m + logf(s);
    out[(size_t)wid * 80 + lane] = v0 - ls;
    if (lane < 16) out[(size_t)wid * 80 + 64 + lane] = v1 - ls;
}

// ---------------- launch ----------------

extern "C" void kernel_launch(void* const* d_in, const int* in_sizes, int n_in,
                              void* d_out, int out_size, void* d_ws, size_t ws_size,
                              hipStream_t stream) {
    const float* x       = (const float*)d_in[0];
    const int*   e1      = (const int*)d_in[1];
    const int*   e2      = (const int*)d_in[2];
    const float* W_src1  = (const float*)d_in[3];
    const float* W_dst1  = (const float*)d_in[4];
    const float* W_dst21 = (const float*)d_in[5];
    const float* a_src1  = (const float*)d_in[6];
    const float* a_dst1  = (const float*)d_in[7];
    const float* a_dst21 = (const float*)d_in[8];
    const float* W_src2  = (const float*)d_in[9];
    const float* W_dst2  = (const float*)d_in[10];
    const float* W_dst22 = (const float*)d_in[11];
    const float* a_src2  = (const float*)d_in[12];
    const float* a_dst2  = (const float*)d_in[13];
    const float* a_dst22 = (const float*)d_in[14];
    float* out = (float*)d_out;

    const int FIN = 500;
    int n  = in_sizes[0] / FIN;     // 50000
    int E1 = in_sizes[1] / 2;       // 300000
    int E2 = in_sizes[2] / 2;       // ~1.7M
    const int* src1 = e1, *dst1 = e1 + E1;
    const int* src2 = e2, *dst2 = e2 + E2;
    int nb = (n + 511) >> 9;        // 98
    int nsk = (n + 2047) / 2048;    // scan blocks (25)

    char* w = (char*)d_ws;
    auto alloc = [&](size_t bytes) -> char* {
        char* p = w; w += (bytes + 255) & ~(size_t)255; return p;
    };
    u16*   xb1  = (u16*)alloc((size_t)n * 128 * 2);   // layer1 feats bf16 [n][128]
    float* alb1 = (float*)alloc((size_t)n * 16 * 4);  // [als(4)|ald1(4)|ald21(4)|pad]
    u16*   hbuf = (u16*)alloc((size_t)n * 256 * 2);   // elu(concat) hidden bf16 [n][256]
    u16*   xb2  = (u16*)alloc((size_t)n * 40 * 2);    // layer2 feats bf16 [n][40]
    float* alb2 = (float*)alloc((size_t)n * 4 * 4);   // [als|ald1|ald22|pad]
    float* h2   = (float*)alloc((size_t)n * 80 * 4);  // pre-logsoftmax fp32
    u16*   Bt1  = (u16*)alloc(144 * 512 * 2);
    u16*   Bt2  = (u16*)alloc(48 * 256 * 2);
    int* ptr1 = (int*)alloc((size_t)(n + 1) * 4);
    int* cur1 = (int*)alloc((size_t)n * 4);
    int* deg1 = (int*)alloc((size_t)n * 4);
    int* csr1 = (int*)alloc((size_t)E1 * 4);
    int* ptr2 = (int*)alloc((size_t)(n + 1) * 4);
    int* cur2 = (int*)alloc((size_t)n * 4);
    int* deg2 = (int*)alloc((size_t)n * 4);
    int* csr2 = (int*)alloc((size_t)E2 * 4);
    int* bcur1 = (int*)alloc((NB + 1) * 4);
    int* bcur2 = (int*)alloc((NB + 1) * 4);
    int* bsum1 = (int*)alloc(64 * 4);
    int* bsum2 = (int*)alloc(64 * 4);
    // partition scratch aliases h2 (dead until k_prop2; stream-ordered)
    u32* part2 = (u32*)h2;
    u32* part1 = part2 + E2;

    // CSR build
    hipMemsetAsync(deg1, 0, (size_t)n * 4, stream);
    hipMemsetAsync(deg2, 0, (size_t)n * 4, stream);
    k_hist<<<(E1 + 255) / 256, 256, 0, stream>>>(deg1, dst1, E1);
    k_hist<<<(E2 + 255) / 256, 256, 0, stream>>>(deg2, dst2, E2);
    k_scan_a<<<nsk, 256, 0, stream>>>(deg1, bsum1, n);
    k_scan_a<<<nsk, 256, 0, stream>>>(deg2, bsum2, n);
    k_scan_b<<<1, 64, 0, stream>>>(bsum1, ptr1 + n, nsk);
    k_scan_b<<<1, 64, 0, stream>>>(bsum2, ptr2 + n, nsk);
    k_scan_c<<<nsk, 256, 0, stream>>>(deg1, bsum1, ptr1, cur1, bcur1, n);
    k_scan_c<<<nsk, 256, 0, stream>>>(deg2, bsum2, ptr2, cur2, bcur2, n);
    k_part<<<(E1 + 2047) / 2048, 256, 0, stream>>>(src1, dst1, E1, bcur1, part1);
    k_part<<<(E2 + 2047) / 2048, 256, 0, stream>>>(src2, dst2, E2, bcur2, part2);
    k_scat2<<<(E1 + 255) / 256, 256, 0, stream>>>(part1, ptr1, cur1, csr1, E1, n, nb);
    k_scat2<<<(E2 + 255) / 256, 256, 0, stream>>>(part2, ptr2, cur2, csr2, E2, n, nb);

    // layer 1: fused MFMA GEMM (features + attention-logit projections)
    k_build_Bt1<<<(144 * 512 + 255) / 256, 256, 0, stream>>>(W_src1, W_dst1, W_dst21,
                                                             a_src1, a_dst1, a_dst21, Bt1);
    k_mgemm1<<<(n + 63) / 64, 256, 0, stream>>>(x, Bt1, xb1, alb1, n);

    // layer 1 propagate (+ fused ELU), bf16 hidden out
    int pblocks = (n + 3) / 4;
    k_prop1<<<pblocks, 256, 0, stream>>>(ptr1, csr1, alb1, 4, (const uint2*)xb1, hbuf + 0, n);
    k_prop1<<<pblocks, 256, 0, stream>>>(ptr2, csr2, alb1, 8, (const uint2*)xb1, hbuf + 128, n);

    // layer 2: MFMA GEMM on bf16 hidden
    k_build_Bt2<<<(48 * 256 + 255) / 256, 256, 0, stream>>>(W_src2, W_dst2, W_dst22,
                                                            a_src2, a_dst2, a_dst22, Bt2);
    k_mgemm2<<<(n + 63) / 64, 256, 0, stream>>>(hbuf, Bt2, xb2, alb2, n);

    // layer 2 propagate
    k_prop2<<<pblocks, 256, 0, stream>>>(ptr1, csr1, alb2, 1, (const uint2*)xb2, h2 + 0, n);
    k_prop2<<<pblocks, 256, 0, stream>>>(ptr2, csr2, alb2, 2, (const uint2*)xb2, h2 + 40, n);

    // log_softmax
    k_lsm<<<pblocks, 256, 0, stream>>>(h2, out, n);
}

// Round 6
// 354.414 us; speedup vs baseline: 3.4673x; 1.1333x over previous
//
#include <hip/hip_runtime.h>
#include <hip/hip_bf16.h>
#include <math.h>

typedef unsigned short u16;
typedef unsigned int u32;
typedef __attribute__((ext_vector_type(8))) short short8;
typedef __attribute__((ext_vector_type(4))) float f32x4;

#define NB 128  // bucket slots (actual buckets = ceil(n/512) = 98 for n=50000)

static __device__ __forceinline__ u16 f2bf(float f) {
    u32 u = __float_as_uint(f);
    u32 r = (u + 0x7fffu + ((u >> 16) & 1u)) >> 16;
    return (u16)r;
}
static __device__ __forceinline__ float bl(u32 u) { return __uint_as_float(u << 16); }
static __device__ __forceinline__ float bh(u32 u) { return __uint_as_float(u & 0xffff0000u); }

// ---------------- CSR build (bucket-first, no per-node atomics) ----------------

// per-block LDS histogram of bucket ids -> bcnt[nb]
__global__ __launch_bounds__(256) void k_bhist(const int* __restrict__ dst, int E,
                                               int* __restrict__ bcnt) {
    __shared__ int lh[NB];
    int tid = threadIdx.x;
    int base = blockIdx.x * 2048;
    for (int i = tid; i < NB; i += 256) lh[i] = 0;
    __syncthreads();
    int cnt = min(2048, E - base);
    #pragma unroll
    for (int k = 0; k < 8; k++) {
        int i = tid + k * 256;
        if (i < cnt) atomicAdd(&lh[dst[base + i] >> 9], 1);
    }
    __syncthreads();
    for (int i = tid; i < NB; i += 256) {
        int c = lh[i];
        if (c) atomicAdd(&bcnt[i], c);
    }
}

// single block: exclusive scan of bucket counts -> bbase[nb+1], bcur; ptr[n]=E
__global__ void k_bscan(const int* __restrict__ bcnt, int* __restrict__ bbase,
                        int* __restrict__ bcur, int* __restrict__ ptrN, int nb) {
    __shared__ int sh[NB];
    int t = threadIdx.x;  // 128
    int v = (t < nb) ? bcnt[t] : 0;
    sh[t] = v;
    __syncthreads();
    for (int off = 1; off < NB; off <<= 1) {
        int val = sh[t];
        int add = (t >= off) ? sh[t - off] : 0;
        __syncthreads();
        sh[t] = val + add;
        __syncthreads();
    }
    int excl = sh[t] - v;
    if (t <= nb) bbase[t] = excl;
    if (t < nb) bcur[t] = excl;
    if (t == nb) *ptrN = excl;   // total = E
}

// partition edges into dst-buckets of 512; packed record (dstLow9<<16)|src16
__global__ __launch_bounds__(256) void k_part(const int* __restrict__ src,
                                              const int* __restrict__ dst, int E,
                                              int* __restrict__ bcur,
                                              u32* __restrict__ part) {
    __shared__ int lh[NB];
    __shared__ int gb[NB];
    int tid = threadIdx.x;
    int base = blockIdx.x * 2048;
    for (int i = tid; i < NB; i += 256) lh[i] = 0;
    __syncthreads();
    int cnt = min(2048, E - base);
    int bkt[8], rank[8]; u32 pk[8];
    #pragma unroll
    for (int k = 0; k < 8; k++) {
        int i = tid + k * 256;
        if (i < cnt) {
            int s = src[base + i], d = dst[base + i];
            int b = d >> 9;
            bkt[k] = b;
            pk[k] = ((u32)(d & 511) << 16) | (u32)s;
            rank[k] = atomicAdd(&lh[b], 1);
        } else bkt[k] = -1;
    }
    __syncthreads();
    for (int i = tid; i < NB; i += 256) {
        int c = lh[i];
        gb[i] = c ? atomicAdd(&bcur[i], c) : 0;
    }
    __syncthreads();
    #pragma unroll
    for (int k = 0; k < 8; k++)
        if (bkt[k] >= 0) part[gb[bkt[k]] + rank[k]] = pk[k];
}

// per-bucket: histogram dstLow9 from contiguous part slice + in-LDS scan -> ptr, cur
__global__ __launch_bounds__(256) void k_dhs(const u32* __restrict__ part,
                                             const int* __restrict__ bbase,
                                             int* __restrict__ ptrArr, int* __restrict__ cur,
                                             int n) {
    __shared__ int hist[512];
    __shared__ int tsum[256];
    int b = blockIdx.x;
    int t = threadIdx.x;
    int lo = bbase[b], hi = bbase[b + 1];
    hist[t] = 0; hist[t + 256] = 0;
    __syncthreads();
    for (int i = lo + t; i < hi; i += 256)
        atomicAdd(&hist[(part[i] >> 16) & 511], 1);
    __syncthreads();
    int v0 = hist[2 * t], v1 = hist[2 * t + 1];
    tsum[t] = v0 + v1;
    __syncthreads();
    for (int off = 1; off < 256; off <<= 1) {
        int val = tsum[t];
        int add = (t >= off) ? tsum[t - off] : 0;
        __syncthreads();
        tsum[t] = val + add;
        __syncthreads();
    }
    int basep = lo + ((t == 0) ? 0 : tsum[t - 1]);
    int i0 = (b << 9) + 2 * t;
    if (i0 < n)     { ptrArr[i0] = basep;      cur[i0] = basep; }
    if (i0 + 1 < n) { ptrArr[i0 + 1] = basep + v0; cur[i0 + 1] = basep + v0; }
}

// in-bucket scatter (cursor + store windows are L2-resident)
__global__ __launch_bounds__(256) void k_scat2(const u32* __restrict__ part,
                                               const int* __restrict__ ptrArr,
                                               int* __restrict__ cur,
                                               int* __restrict__ csr, int E, int n, int nb) {
    __shared__ int bb[NB + 1];
    int tid = threadIdx.x;
    for (int i = tid; i <= nb; i += 256) bb[i] = ptrArr[min(i << 9, n)];
    __syncthreads();
    int i = blockIdx.x * 256 + tid;
    if (i < E) {
        u32 pk = part[i];
        int lo = 0, hi = nb;
        #pragma unroll
        for (int t = 0; t < 7; t++) {
            int mid = (lo + hi) >> 1;
            if (bb[mid] <= i) lo = mid; else hi = mid;
        }
        int d = (lo << 9) + (int)(pk >> 16);
        int pos = atomicAdd(&cur[d], 1);
        csr[pos] = (int)(pk & 0xffffu);
    }
}

// ---------------- weight prep (transposed bf16 B matrices) ----------------
__global__ void k_build_Bt1(const float* __restrict__ Ws, const float* __restrict__ Wd,
                            const float* __restrict__ Wd2, const float* __restrict__ as_,
                            const float* __restrict__ ad, const float* __restrict__ ad2,
                            u16* __restrict__ Bt) {
    int t = blockIdx.x * blockDim.x + threadIdx.x;
    if (t >= 144 * 512) return;
    int nn = t >> 9, k = t & 511;
    float v = 0.f;
    if (k < 500) {
        if (nn < 128) v = Ws[k * 128 + nn];
        else if (nn < 140) {
            int q = nn - 128; int h = q & 3;
            const float* W; const float* a;
            if (q < 4)      { W = Ws;  a = as_; }
            else if (q < 8) { W = Wd;  a = ad;  }
            else            { W = Wd2; a = ad2; }
            float s = 0.f;
            #pragma unroll 8
            for (int c = 0; c < 32; c++) s += W[k * 128 + h * 32 + c] * a[h * 32 + c];
            v = s;
        }
    }
    Bt[t] = f2bf(v);
}

__global__ void k_build_Bt2(const float* __restrict__ Ws, const float* __restrict__ Wd,
                            const float* __restrict__ Wd2, const float* __restrict__ as_,
                            const float* __restrict__ ad, const float* __restrict__ ad2,
                            u16* __restrict__ Bt) {
    int t = blockIdx.x * blockDim.x + threadIdx.x;
    if (t >= 48 * 256) return;
    int nn = t >> 8, k = t & 255;
    float v = 0.f;
    if (nn < 40) v = Ws[k * 40 + nn];
    else if (nn < 43) {
        const float* a = (nn == 40) ? as_ : (nn == 41) ? ad : ad2;
        const float* W = Ws;
        if (nn == 41) W = Wd; else if (nn == 42) W = Wd2;
        float s = 0.f;
        #pragma unroll 8
        for (int c = 0; c < 40; c++) s += W[k * 40 + c] * a[c];
        v = s;
    }
    Bt[t] = f2bf(v);
}

// ---------------- MFMA GEMM layer 1 ----------------
__global__ __launch_bounds__(256) void k_mgemm1(const float* __restrict__ A,
                                                const u16* __restrict__ Bt,
                                                u16* __restrict__ xb,
                                                float* __restrict__ alb, int M) {
    __shared__ __align__(16) u16 As[64][40];
    __shared__ __align__(16) u16 Bs[144][40];
    int tid = threadIdx.x;
    int wv = tid >> 6, lane = tid & 63;
    int l15 = lane & 15, k8 = lane >> 4;
    int rowBlk = blockIdx.x * 64;

    f32x4 acc[9];
    #pragma unroll
    for (int t = 0; t < 9; t++) acc[t] = (f32x4){0.f, 0.f, 0.f, 0.f};

    int r = tid >> 2, kc = (tid & 3) * 8;
    bool rowOK = (rowBlk + r) < M;
    const float* Ap0 = A + (size_t)(rowBlk + r) * 500;

    for (int k0 = 0; k0 < 512; k0 += 32) {
        float v[8];
        const float* Ap = Ap0 + k0 + kc;
        if (rowOK && (k0 + kc + 8 <= 500)) {
            float4 p0 = *(const float4*)Ap;
            float4 p1 = *(const float4*)(Ap + 4);
            v[0] = p0.x; v[1] = p0.y; v[2] = p0.z; v[3] = p0.w;
            v[4] = p1.x; v[5] = p1.y; v[6] = p1.z; v[7] = p1.w;
        } else {
            #pragma unroll
            for (int i = 0; i < 8; i++) {
                int gk = k0 + kc + i;
                v[i] = (rowOK && gk < 500) ? Ap[i] : 0.f;
            }
        }
        uint4 pk;
        pk.x = (u32)f2bf(v[0]) | ((u32)f2bf(v[1]) << 16);
        pk.y = (u32)f2bf(v[2]) | ((u32)f2bf(v[3]) << 16);
        pk.z = (u32)f2bf(v[4]) | ((u32)f2bf(v[5]) << 16);
        pk.w = (u32)f2bf(v[6]) | ((u32)f2bf(v[7]) << 16);
        *(uint4*)&As[r][kc] = pk;
        for (int idx = tid; idx < 144 * 4; idx += 256) {
            int nn = idx >> 2, c = (idx & 3) * 8;
            *(uint4*)&Bs[nn][c] = *(const uint4*)&Bt[nn * 512 + k0 + c];
        }
        __syncthreads();
        short8 af = *(const short8*)&As[wv * 16 + l15][k8 * 8];
        #pragma unroll
        for (int t = 0; t < 9; t++) {
            short8 bf = *(const short8*)&Bs[t * 16 + l15][k8 * 8];
            acc[t] = __builtin_amdgcn_mfma_f32_16x16x32_bf16(af, bf, acc[t], 0, 0, 0);
        }
        __syncthreads();
    }
    #pragma unroll
    for (int t = 0; t < 9; t++) {
        #pragma unroll
        for (int rr = 0; rr < 4; rr++) {
            int grow = rowBlk + wv * 16 + k8 * 4 + rr;
            if (grow < M) {
                if (t < 8) {
                    xb[(size_t)grow * 128 + t * 16 + l15] = f2bf(acc[t][rr]);
                } else if (l15 < 12) {
                    alb[(size_t)grow * 16 + l15] = acc[t][rr];
                }
            }
        }
    }
}

// ---------------- MFMA GEMM layer 2 ----------------
__global__ __launch_bounds__(256) void k_mgemm2(const u16* __restrict__ A,
                                                const u16* __restrict__ Bt,
                                                u16* __restrict__ xb,
                                                float* __restrict__ alb, int M) {
    __shared__ __align__(16) u16 As[64][40];
    __shared__ __align__(16) u16 Bs[48][40];
    int tid = threadIdx.x;
    int wv = tid >> 6, lane = tid & 63;
    int l15 = lane & 15, k8 = lane >> 4;
    int rowBlk = blockIdx.x * 64;

    f32x4 acc[3];
    #pragma unroll
    for (int t = 0; t < 3; t++) acc[t] = (f32x4){0.f, 0.f, 0.f, 0.f};

    int r = tid >> 2, kc = (tid & 3) * 8;
    bool rowOK = (rowBlk + r) < M;
    const u16* Ap0 = A + (size_t)(rowBlk + r) * 256;

    for (int k0 = 0; k0 < 256; k0 += 32) {
        uint4 pk = {0, 0, 0, 0};
        if (rowOK) pk = *(const uint4*)(Ap0 + k0 + kc);
        *(uint4*)&As[r][kc] = pk;
        if (tid < 48 * 4) {
            int nn = tid >> 2, c = (tid & 3) * 8;
            *(uint4*)&Bs[nn][c] = *(const uint4*)&Bt[nn * 256 + k0 + c];
        }
        __syncthreads();
        short8 af = *(const short8*)&As[wv * 16 + l15][k8 * 8];
        #pragma unroll
        for (int t = 0; t < 3; t++) {
            short8 bf = *(const short8*)&Bs[t * 16 + l15][k8 * 8];
            acc[t] = __builtin_amdgcn_mfma_f32_16x16x32_bf16(af, bf, acc[t], 0, 0, 0);
        }
        __syncthreads();
    }
    #pragma unroll
    for (int t = 0; t < 3; t++) {
        #pragma unroll
        for (int rr = 0; rr < 4; rr++) {
            int grow = rowBlk + wv * 16 + k8 * 4 + rr;
            if (grow < M) {
                int col = t * 16 + l15;
                if (col < 40) xb[(size_t)grow * 40 + col] = f2bf(acc[t][rr]);
                else if (col < 43) alb[(size_t)grow * 4 + (col - 40)] = acc[t][rr];
            }
        }
    }
}

// ---------------- layer-1 propagate ----------------
__global__ __launch_bounds__(256) void k_prop1(const int* __restrict__ ptr, const int* __restrict__ csr,
                                               const float* __restrict__ al, int doff,
                                               const uint2* __restrict__ xbv,
                                               u16* __restrict__ out, int n) {
    __shared__ int sbuf[4][64];
    __shared__ __align__(16) float wbuf[4][64][4];
    int tid = threadIdx.x;
    int wv = tid >> 6, lane = tid & 63;
    int wid = (blockIdx.x * 256 + tid) >> 6;
    if (wid >= n) return;
    int b = ptr[wid], e = ptr[wid + 1];
    float4 adv = *(const float4*)(al + (size_t)wid * 16 + doff);
    int l5 = lane & 31, h2 = l5 >> 3, half = lane >> 5;

    float acc0 = 0.f, acc1 = 0.f, acc2 = 0.f, acc3 = 0.f;
    float dn0 = 0.f, dn1 = 0.f, dn2 = 0.f, dn3 = 0.f;

    for (int cb = b; cb < e; cb += 64) {
        int cnt = min(64, e - cb);
        int s = 0;
        float w0 = 0.f, w1 = 0.f, w2 = 0.f, w3 = 0.f;
        if (lane < cnt) {
            s = csr[cb + lane];
            float4 av = *(const float4*)(al + (size_t)s * 16);
            float a0 = av.x + adv.x; a0 = a0 > 0.f ? a0 : 0.2f * a0; w0 = __expf(a0);
            float a1 = av.y + adv.y; a1 = a1 > 0.f ? a1 : 0.2f * a1; w1 = __expf(a1);
            float a2 = av.z + adv.z; a2 = a2 > 0.f ? a2 : 0.2f * a2; w2 = __expf(a2);
            float a3 = av.w + adv.w; a3 = a3 > 0.f ? a3 : 0.2f * a3; w3 = __expf(a3);
        }
        dn0 += w0; dn1 += w1; dn2 += w2; dn3 += w3;
        sbuf[wv][lane] = s;
        float4 wq; wq.x = w0; wq.y = w1; wq.z = w2; wq.w = w3;
        *(float4*)&wbuf[wv][lane][0] = wq;
        #pragma unroll 4
        for (int j = 0; j < cnt; j += 2) {
            int jj = j + half;
            int sj = sbuf[wv][jj];
            float wj = wbuf[wv][jj][h2];
            uint2 pk = xbv[(size_t)sj * 32 + l5];
            acc0 = fmaf(wj, bl(pk.x), acc0);
            acc1 = fmaf(wj, bh(pk.x), acc1);
            acc2 = fmaf(wj, bl(pk.y), acc2);
            acc3 = fmaf(wj, bh(pk.y), acc3);
        }
    }
    acc0 += __shfl_xor(acc0, 32);
    acc1 += __shfl_xor(acc1, 32);
    acc2 += __shfl_xor(acc2, 32);
    acc3 += __shfl_xor(acc3, 32);
    #pragma unroll
    for (int o = 32; o > 0; o >>= 1) {
        dn0 += __shfl_xor(dn0, o);
        dn1 += __shfl_xor(dn1, o);
        dn2 += __shfl_xor(dn2, o);
        dn3 += __shfl_xor(dn3, o);
    }
    float dh = (h2 == 0) ? dn0 : (h2 == 1) ? dn1 : (h2 == 2) ? dn2 : dn3;
    float inv = 1.f / (dh + 1e-16f);
    float r0 = acc0 * inv, r1 = acc1 * inv, r2 = acc2 * inv, r3 = acc3 * inv;
    r0 = r0 > 0.f ? r0 : __expf(r0) - 1.f;
    r1 = r1 > 0.f ? r1 : __expf(r1) - 1.f;
    r2 = r2 > 0.f ? r2 : __expf(r2) - 1.f;
    r3 = r3 > 0.f ? r3 : __expf(r3) - 1.f;
    if (half == 0) {
        uint2 st;
        st.x = (u32)f2bf(r0) | ((u32)f2bf(r1) << 16);
        st.y = (u32)f2bf(r2) | ((u32)f2bf(r3) << 16);
        *(uint2*)(out + (size_t)wid * 256 + 4 * l5) = st;
    }
}

// ---------------- layer-2 propagate ----------------
__global__ __launch_bounds__(256) void k_prop2(const int* __restrict__ ptr, const int* __restrict__ csr,
                                               const float* __restrict__ al, int didx,
                                               const uint2* __restrict__ xbv,
                                               float* __restrict__ out, int n) {
    __shared__ int2 swb[4][64];
    int tid = threadIdx.x;
    int wv = tid >> 6, lane = tid & 63;
    int wid = (blockIdx.x * 256 + tid) >> 6;
    if (wid >= n) return;
    int b = ptr[wid], e = ptr[wid + 1];
    float ad = al[(size_t)wid * 4 + didx];
    int g = lane / 10;
    int cp = lane - g * 10;
    bool act = g < 6;

    float acc0 = 0.f, acc1 = 0.f, acc2 = 0.f, acc3 = 0.f;
    float den = 0.f;

    for (int cb = b; cb < e; cb += 64) {
        int cnt = min(64, e - cb);
        int s = 0; float w = 0.f;
        if (lane < cnt) {
            s = csr[cb + lane];
            float a = al[(size_t)s * 4] + ad;
            a = a > 0.f ? a : 0.2f * a;
            w = __expf(a);
        }
        den += w;
        swb[wv][lane] = make_int2(s, __float_as_int(w));
        #pragma unroll 2
        for (int j = 0; j < cnt; j += 6) {
            int jj = j + g;
            bool valid = act && (jj < cnt);
            int2 sw = swb[wv][valid ? jj : 0];
            float wj = valid ? __int_as_float(sw.y) : 0.f;
            uint2 pk = xbv[(size_t)sw.x * 10 + cp];
            acc0 = fmaf(wj, bl(pk.x), acc0);
            acc1 = fmaf(wj, bh(pk.x), acc1);
            acc2 = fmaf(wj, bl(pk.y), acc2);
            acc3 = fmaf(wj, bh(pk.y), acc3);
        }
    }
    float t0;
    t0 = acc0 + __shfl(acc0, (lane + 30) & 63); acc0 = t0 + __shfl(t0, (lane + 10) & 63) + __shfl(t0, (lane + 20) & 63);
    t0 = acc1 + __shfl(acc1, (lane + 30) & 63); acc1 = t0 + __shfl(t0, (lane + 10) & 63) + __shfl(t0, (lane + 20) & 63);
    t0 = acc2 + __shfl(acc2, (lane + 30) & 63); acc2 = t0 + __shfl(t0, (lane + 10) & 63) + __shfl(t0, (lane + 20) & 63);
    t0 = acc3 + __shfl(acc3, (lane + 30) & 63); acc3 = t0 + __shfl(t0, (lane + 10) & 63) + __shfl(t0, (lane + 20) & 63);
    #pragma unroll
    for (int o = 32; o > 0; o >>= 1) den += __shfl_xor(den, o);
    if (lane < 10) {
        float inv = 1.f / (den + 1e-16f);
        float4 st; st.x = acc0 * inv; st.y = acc1 * inv; st.z = acc2 * inv; st.w = acc3 * inv;
        *(float4*)(out + (size_t)wid * 80 + 4 * cp) = st;
    }
}

// ---------------- log_softmax ----------------
__global__ __launch_bounds__(256) void k_lsm(const float* __restrict__ h2, float* __restrict__ out, int n) {
    int wid = (blockIdx.x * blockDim.x + threadIdx.x) >> 6;
    int lane = threadIdx.x & 63;
    if (wid >= n) return;
    const float* row = h2 + (size_t)wid * 80;
    float v0 = row[lane];
    float v1 = (lane < 16) ? row[64 + lane] : -INFINITY;
    float m = fmaxf(v0, v1);
    for (int o = 32; o > 0; o >>= 1) m = fmaxf(m, __shfl_xor(m, o));
    float s = __expf(v0 - m) + ((lane < 16) ? __expf(v1 - m) : 0.f);
    for (int o = 32; o > 0; o >>= 1) s += __shfl_xor(s, o);
    float ls = m + logf(s);
    out[(size_t)wid * 80 + lane] = v0 - ls;
    if (lane < 16) out[(size_t)wid * 80 + 64 + lane] = v1 - ls;
}

// ---------------- launch ----------------

extern "C" void kernel_launch(void* const* d_in, const int* in_sizes, int n_in,
                              void* d_out, int out_size, void* d_ws, size_t ws_size,
                              hipStream_t stream) {
    const float* x       = (const float*)d_in[0];
    const int*   e1      = (const int*)d_in[1];
    const int*   e2      = (const int*)d_in[2];
    const float* W_src1  = (const float*)d_in[3];
    const float* W_dst1  = (const float*)d_in[4];
    const float* W_dst21 = (const float*)d_in[5];
    const float* a_src1  = (const float*)d_in[6];
    const float* a_dst1  = (const float*)d_in[7];
    const float* a_dst21 = (const float*)d_in[8];
    const float* W_src2  = (const float*)d_in[9];
    const float* W_dst2  = (const float*)d_in[10];
    const float* W_dst22 = (const float*)d_in[11];
    const float* a_src2  = (const float*)d_in[12];
    const float* a_dst2  = (const float*)d_in[13];
    const float* a_dst22 = (const float*)d_in[14];
    float* out = (float*)d_out;

    const int FIN = 500;
    int n  = in_sizes[0] / FIN;     // 50000
    int E1 = in_sizes[1] / 2;       // 300000
    int E2 = in_sizes[2] / 2;       // ~1.7M
    const int* src1 = e1, *dst1 = e1 + E1;
    const int* src2 = e2, *dst2 = e2 + E2;
    int nb = (n + 511) >> 9;        // 98

    char* w = (char*)d_ws;
    auto alloc = [&](size_t bytes) -> char* {
        char* p = w; w += (bytes + 255) & ~(size_t)255; return p;
    };
    u16*   xb1  = (u16*)alloc((size_t)n * 128 * 2);   // layer1 feats bf16 [n][128]
    float* alb1 = (float*)alloc((size_t)n * 16 * 4);  // [als(4)|ald1(4)|ald21(4)|pad]
    u16*   hbuf = (u16*)alloc((size_t)n * 256 * 2);   // elu(concat) hidden bf16 [n][256]
    u16*   xb2  = (u16*)alloc((size_t)n * 40 * 2);    // layer2 feats bf16 [n][40]
    float* alb2 = (float*)alloc((size_t)n * 4 * 4);   // [als|ald1|ald22|pad]
    float* h2   = (float*)alloc((size_t)n * 80 * 4);  // pre-logsoftmax fp32
    u16*   Bt1  = (u16*)alloc(144 * 512 * 2);
    u16*   Bt2  = (u16*)alloc(48 * 256 * 2);
    int* ptr1 = (int*)alloc((size_t)(n + 1) * 4);
    int* cur1 = (int*)alloc((size_t)n * 4);
    int* csr1 = (int*)alloc((size_t)E1 * 4);
    int* ptr2 = (int*)alloc((size_t)(n + 1) * 4);
    int* cur2 = (int*)alloc((size_t)n * 4);
    int* csr2 = (int*)alloc((size_t)E2 * 4);
    int* bcnt1  = (int*)alloc(NB * 4);
    int* bcnt2  = (int*)alloc(NB * 4);
    int* bbase1 = (int*)alloc((NB + 1) * 4);
    int* bbase2 = (int*)alloc((NB + 1) * 4);
    int* bcur1  = (int*)alloc(NB * 4);
    int* bcur2  = (int*)alloc(NB * 4);
    // partition scratch aliases h2 (dead until k_prop2; stream-ordered)
    u32* part2 = (u32*)h2;
    u32* part1 = part2 + E2;

    // CSR build (bucket-first)
    hipMemsetAsync(bcnt1, 0, NB * 4, stream);
    hipMemsetAsync(bcnt2, 0, NB * 4, stream);
    k_bhist<<<(E1 + 2047) / 2048, 256, 0, stream>>>(dst1, E1, bcnt1);
    k_bhist<<<(E2 + 2047) / 2048, 256, 0, stream>>>(dst2, E2, bcnt2);
    k_bscan<<<1, NB, 0, stream>>>(bcnt1, bbase1, bcur1, ptr1 + n, nb);
    k_bscan<<<1, NB, 0, stream>>>(bcnt2, bbase2, bcur2, ptr2 + n, nb);
    k_part<<<(E1 + 2047) / 2048, 256, 0, stream>>>(src1, dst1, E1, bcur1, part1);
    k_part<<<(E2 + 2047) / 2048, 256, 0, stream>>>(src2, dst2, E2, bcur2, part2);
    k_dhs<<<nb, 256, 0, stream>>>(part1, bbase1, ptr1, cur1, n);
    k_dhs<<<nb, 256, 0, stream>>>(part2, bbase2, ptr2, cur2, n);
    k_scat2<<<(E1 + 255) / 256, 256, 0, stream>>>(part1, ptr1, cur1, csr1, E1, n, nb);
    k_scat2<<<(E2 + 255) / 256, 256, 0, stream>>>(part2, ptr2, cur2, csr2, E2, n, nb);

    // layer 1: fused MFMA GEMM (features + attention-logit projections)
    k_build_Bt1<<<(144 * 512 + 255) / 256, 256, 0, stream>>>(W_src1, W_dst1, W_dst21,
                                                             a_src1, a_dst1, a_dst21, Bt1);
    k_mgemm1<<<(n + 63) / 64, 256, 0, stream>>>(x, Bt1, xb1, alb1, n);

    // layer 1 propagate (+ fused ELU), bf16 hidden out
    int pblocks = (n + 3) / 4;
    k_prop1<<<pblocks, 256, 0, stream>>>(ptr1, csr1, alb1, 4, (const uint2*)xb1, hbuf + 0, n);
    k_prop1<<<pblocks, 256, 0, stream>>>(ptr2, csr2, alb1, 8, (const uint2*)xb1, hbuf + 128, n);

    // layer 2: MFMA GEMM on bf16 hidden
    k_build_Bt2<<<(48 * 256 + 255) / 256, 256, 0, stream>>>(W_src2, W_dst2, W_dst22,
                                                            a_src2, a_dst2, a_dst22, Bt2);
    k_mgemm2<<<(n + 63) / 64, 256, 0, stream>>>(hbuf, Bt2, xb2, alb2, n);

    // layer 2 propagate
    k_prop2<<<pblocks, 256, 0, stream>>>(ptr1, csr1, alb2, 1, (const uint2*)xb2, h2 + 0, n);
    k_prop2<<<pblocks, 256, 0, stream>>>(ptr2, csr2, alb2, 2, (const uint2*)xb2, h2 + 40, n);

    // log_softmax
    k_lsm<<<pblocks, 256, 0, stream>>>(h2, out, n);
}

// Round 7
// 298.203 us; speedup vs baseline: 4.1209x; 1.1885x over previous
//
#include <hip/hip_runtime.h>
#include <hip/hip_bf16.h>
#include <math.h>

typedef unsigned short u16;
typedef unsigned int u32;
typedef unsigned char u8;
typedef __attribute__((ext_vector_type(8))) short short8;
typedef __attribute__((ext_vector_type(4))) float f32x4;
typedef __attribute__((ext_vector_type(2))) float f32x2;

#define NB 128  // bucket slots (actual buckets = ceil(n/512) = 98 for n=50000)

static __device__ __forceinline__ u16 f2bf(float f) {
    u32 u = __float_as_uint(f);
    u32 r = (u + 0x7fffu + ((u >> 16) & 1u)) >> 16;
    return (u16)r;
}
static __device__ __forceinline__ float bl(u32 u) { return __uint_as_float(u << 16); }
static __device__ __forceinline__ float bh(u32 u) { return __uint_as_float(u & 0xffff0000u); }

// ---------------- CSR build (bucket-first, no per-node global atomics) --------

// per-block LDS histogram of bucket ids -> bcnt[nb]
__global__ __launch_bounds__(256) void k_bhist(const int* __restrict__ dst, int E,
                                               int* __restrict__ bcnt) {
    __shared__ int lh[NB];
    int tid = threadIdx.x;
    int base = blockIdx.x * 2048;
    for (int i = tid; i < NB; i += 256) lh[i] = 0;
    __syncthreads();
    int cnt = min(2048, E - base);
    #pragma unroll
    for (int k = 0; k < 8; k++) {
        int i = tid + k * 256;
        if (i < cnt) atomicAdd(&lh[dst[base + i] >> 9], 1);
    }
    __syncthreads();
    for (int i = tid; i < NB; i += 256) {
        int c = lh[i];
        if (c) atomicAdd(&bcnt[i], c);
    }
}

// single block: exclusive scan of bucket counts -> bbase[nb+1], bcur; ptr[n]=E
__global__ void k_bscan(const int* __restrict__ bcnt, int* __restrict__ bbase,
                        int* __restrict__ bcur, int* __restrict__ ptrN, int nb) {
    __shared__ int sh[NB];
    int t = threadIdx.x;  // 128
    int v = (t < nb) ? bcnt[t] : 0;
    sh[t] = v;
    __syncthreads();
    for (int off = 1; off < NB; off <<= 1) {
        int val = sh[t];
        int add = (t >= off) ? sh[t - off] : 0;
        __syncthreads();
        sh[t] = val + add;
        __syncthreads();
    }
    int excl = sh[t] - v;
    if (t <= nb) bbase[t] = excl;
    if (t < nb) bcur[t] = excl;
    if (t == nb) *ptrN = excl;   // total = E
}

// partition edges into dst-buckets of 512; packed record (dstLow9<<16)|src16
__global__ __launch_bounds__(256) void k_part(const int* __restrict__ src,
                                              const int* __restrict__ dst, int E,
                                              int* __restrict__ bcur,
                                              u32* __restrict__ part) {
    __shared__ int lh[NB];
    __shared__ int gb[NB];
    int tid = threadIdx.x;
    int base = blockIdx.x * 2048;
    for (int i = tid; i < NB; i += 256) lh[i] = 0;
    __syncthreads();
    int cnt = min(2048, E - base);
    int bkt[8], rank[8]; u32 pk[8];
    #pragma unroll
    for (int k = 0; k < 8; k++) {
        int i = tid + k * 256;
        if (i < cnt) {
            int s = src[base + i], d = dst[base + i];
            int b = d >> 9;
            bkt[k] = b;
            pk[k] = ((u32)(d & 511) << 16) | (u32)s;
            rank[k] = atomicAdd(&lh[b], 1);
        } else bkt[k] = -1;
    }
    __syncthreads();
    for (int i = tid; i < NB; i += 256) {
        int c = lh[i];
        gb[i] = c ? atomicAdd(&bcur[i], c) : 0;
    }
    __syncthreads();
    #pragma unroll
    for (int k = 0; k < 8; k++)
        if (bkt[k] >= 0) part[gb[bkt[k]] + rank[k]] = pk[k];
}

// per-bucket: hist of dstLow9 + in-LDS scan -> ptr; then scatter slice -> csr16
__global__ __launch_bounds__(256) void k_dhs(const u32* __restrict__ part,
                                             const int* __restrict__ bbase,
                                             int* __restrict__ ptrArr,
                                             u16* __restrict__ csr, int n) {
    __shared__ int hist[512];
    __shared__ int tsum[256];
    int b = blockIdx.x;
    int t = threadIdx.x;
    int lo = bbase[b], hi = bbase[b + 1];
    hist[t] = 0; hist[t + 256] = 0;
    __syncthreads();
    for (int i = lo + t; i < hi; i += 256)
        atomicAdd(&hist[(part[i] >> 16) & 511], 1);
    __syncthreads();
    int v0 = hist[2 * t], v1 = hist[2 * t + 1];
    tsum[t] = v0 + v1;
    __syncthreads();
    for (int off = 1; off < 256; off <<= 1) {
        int val = tsum[t];
        int add = (t >= off) ? tsum[t - off] : 0;
        __syncthreads();
        tsum[t] = val + add;
        __syncthreads();
    }
    int basep = lo + ((t == 0) ? 0 : tsum[t - 1]);
    int i0 = (b << 9) + 2 * t;
    if (i0 < n)     ptrArr[i0] = basep;
    if (i0 + 1 < n) ptrArr[i0 + 1] = basep + v0;
    __syncthreads();
    hist[2 * t] = basep;             // cursors
    hist[2 * t + 1] = basep + v0;
    __syncthreads();
    for (int i = lo + t; i < hi; i += 256) {
        u32 pk = part[i];
        int pos = atomicAdd(&hist[(pk >> 16) & 511], 1);
        csr[pos] = (u16)(pk & 0xffffu);
    }
}

// ---------------- weight prep (transposed bf16 B matrices) ----------------
__global__ void k_build_Bt1(const float* __restrict__ Ws, const float* __restrict__ Wd,
                            const float* __restrict__ Wd2, const float* __restrict__ as_,
                            const float* __restrict__ ad, const float* __restrict__ ad2,
                            u16* __restrict__ Bt) {
    int t = blockIdx.x * blockDim.x + threadIdx.x;
    if (t >= 144 * 512) return;
    int nn = t >> 9, k = t & 511;
    float v = 0.f;
    if (k < 500) {
        if (nn < 128) v = Ws[k * 128 + nn];
        else if (nn < 140) {
            int q = nn - 128; int h = q & 3;
            const float* W; const float* a;
            if (q < 4)      { W = Ws;  a = as_; }
            else if (q < 8) { W = Wd;  a = ad;  }
            else            { W = Wd2; a = ad2; }
            float s = 0.f;
            #pragma unroll 8
            for (int c = 0; c < 32; c++) s += W[k * 128 + h * 32 + c] * a[h * 32 + c];
            v = s;
        }
    }
    Bt[t] = f2bf(v);
}

__global__ void k_build_Bt2(const float* __restrict__ Ws, const float* __restrict__ Wd,
                            const float* __restrict__ Wd2, const float* __restrict__ as_,
                            const float* __restrict__ ad, const float* __restrict__ ad2,
                            u16* __restrict__ Bt) {
    int t = blockIdx.x * blockDim.x + threadIdx.x;
    if (t >= 48 * 256) return;
    int nn = t >> 8, k = t & 255;
    float v = 0.f;
    if (nn < 40) v = Ws[k * 40 + nn];
    else if (nn < 43) {
        const float* a = (nn == 40) ? as_ : (nn == 41) ? ad : ad2;
        const float* W = Ws;
        if (nn == 41) W = Wd; else if (nn == 42) W = Wd2;
        float s = 0.f;
        #pragma unroll 8
        for (int c = 0; c < 40; c++) s += W[k * 40 + c] * a[c];
        v = s;
    }
    Bt[t] = f2bf(v);
}

// ---------------- MFMA GEMM layer 1 (fp8 feature out + fp32 al out) -----------
__global__ __launch_bounds__(256) void k_mgemm1(const float* __restrict__ A,
                                                const u16* __restrict__ Bt,
                                                u8* __restrict__ xb,
                                                float* __restrict__ alb, int M) {
    __shared__ __align__(16) u16 As[64][40];
    __shared__ __align__(16) u16 Bs[144][40];
    int tid = threadIdx.x;
    int wv = tid >> 6, lane = tid & 63;
    int l15 = lane & 15, k8 = lane >> 4;
    int rowBlk = blockIdx.x * 64;

    f32x4 acc[9];
    #pragma unroll
    for (int t = 0; t < 9; t++) acc[t] = (f32x4){0.f, 0.f, 0.f, 0.f};

    int r = tid >> 2, kc = (tid & 3) * 8;
    bool rowOK = (rowBlk + r) < M;
    const float* Ap0 = A + (size_t)(rowBlk + r) * 500;

    for (int k0 = 0; k0 < 512; k0 += 32) {
        float v[8];
        const float* Ap = Ap0 + k0 + kc;
        if (rowOK && (k0 + kc + 8 <= 500)) {
            float4 p0 = *(const float4*)Ap;
            float4 p1 = *(const float4*)(Ap + 4);
            v[0] = p0.x; v[1] = p0.y; v[2] = p0.z; v[3] = p0.w;
            v[4] = p1.x; v[5] = p1.y; v[6] = p1.z; v[7] = p1.w;
        } else {
            #pragma unroll
            for (int i = 0; i < 8; i++) {
                int gk = k0 + kc + i;
                v[i] = (rowOK && gk < 500) ? Ap[i] : 0.f;
            }
        }
        uint4 pk;
        pk.x = (u32)f2bf(v[0]) | ((u32)f2bf(v[1]) << 16);
        pk.y = (u32)f2bf(v[2]) | ((u32)f2bf(v[3]) << 16);
        pk.z = (u32)f2bf(v[4]) | ((u32)f2bf(v[5]) << 16);
        pk.w = (u32)f2bf(v[6]) | ((u32)f2bf(v[7]) << 16);
        *(uint4*)&As[r][kc] = pk;
        for (int idx = tid; idx < 144 * 4; idx += 256) {
            int nn = idx >> 2, c = (idx & 3) * 8;
            *(uint4*)&Bs[nn][c] = *(const uint4*)&Bt[nn * 512 + k0 + c];
        }
        __syncthreads();
        short8 af = *(const short8*)&As[wv * 16 + l15][k8 * 8];
        #pragma unroll
        for (int t = 0; t < 9; t++) {
            short8 bf = *(const short8*)&Bs[t * 16 + l15][k8 * 8];
            acc[t] = __builtin_amdgcn_mfma_f32_16x16x32_bf16(af, bf, acc[t], 0, 0, 0);
        }
        __syncthreads();
    }
    #pragma unroll
    for (int t = 0; t < 9; t++) {
        #pragma unroll
        for (int rr = 0; rr < 4; rr++) {
            int grow = rowBlk + wv * 16 + k8 * 4 + rr;
            if (grow < M) {
                if (t < 8) {
                    u32 p8 = __builtin_amdgcn_cvt_pk_fp8_f32(acc[t][rr], acc[t][rr], 0, false);
                    xb[(size_t)grow * 128 + t * 16 + l15] = (u8)(p8 & 0xffu);
                } else if (l15 < 12) {
                    alb[(size_t)grow * 16 + l15] = acc[t][rr];
                }
            }
        }
    }
}

// ---------------- MFMA GEMM layer 2 ----------------
__global__ __launch_bounds__(256) void k_mgemm2(const u16* __restrict__ A,
                                                const u16* __restrict__ Bt,
                                                u16* __restrict__ xb,
                                                float* __restrict__ alb, int M) {
    __shared__ __align__(16) u16 As[64][40];
    __shared__ __align__(16) u16 Bs[48][40];
    int tid = threadIdx.x;
    int wv = tid >> 6, lane = tid & 63;
    int l15 = lane & 15, k8 = lane >> 4;
    int rowBlk = blockIdx.x * 64;

    f32x4 acc[3];
    #pragma unroll
    for (int t = 0; t < 3; t++) acc[t] = (f32x4){0.f, 0.f, 0.f, 0.f};

    int r = tid >> 2, kc = (tid & 3) * 8;
    bool rowOK = (rowBlk + r) < M;
    const u16* Ap0 = A + (size_t)(rowBlk + r) * 256;

    for (int k0 = 0; k0 < 256; k0 += 32) {
        uint4 pk = {0, 0, 0, 0};
        if (rowOK) pk = *(const uint4*)(Ap0 + k0 + kc);
        *(uint4*)&As[r][kc] = pk;
        if (tid < 48 * 4) {
            int nn = tid >> 2, c = (tid & 3) * 8;
            *(uint4*)&Bs[nn][c] = *(const uint4*)&Bt[nn * 256 + k0 + c];
        }
        __syncthreads();
        short8 af = *(const short8*)&As[wv * 16 + l15][k8 * 8];
        #pragma unroll
        for (int t = 0; t < 3; t++) {
            short8 bf = *(const short8*)&Bs[t * 16 + l15][k8 * 8];
            acc[t] = __builtin_amdgcn_mfma_f32_16x16x32_bf16(af, bf, acc[t], 0, 0, 0);
        }
        __syncthreads();
    }
    #pragma unroll
    for (int t = 0; t < 3; t++) {
        #pragma unroll
        for (int rr = 0; rr < 4; rr++) {
            int grow = rowBlk + wv * 16 + k8 * 4 + rr;
            if (grow < M) {
                int col = t * 16 + l15;
                if (col < 40) xb[(size_t)grow * 40 + col] = f2bf(acc[t][rr]);
                else if (col < 43) alb[(size_t)grow * 4 + (col - 40)] = acc[t][rr];
            }
        }
    }
}

// ---------------- layer-1 propagate (fp8 gather) ----------------
__global__ __launch_bounds__(256) void k_prop1(const int* __restrict__ ptr, const u16* __restrict__ csr,
                                               const float* __restrict__ al, int doff,
                                               const u32* __restrict__ xbv,
                                               u16* __restrict__ out, int n) {
    __shared__ int sbuf[4][64];
    __shared__ __align__(16) float wbuf[4][64][4];
    int tid = threadIdx.x;
    int wv = tid >> 6, lane = tid & 63;
    int wid = (blockIdx.x * 256 + tid) >> 6;
    if (wid >= n) return;
    int b = ptr[wid], e = ptr[wid + 1];
    float4 adv = *(const float4*)(al + (size_t)wid * 16 + doff);
    int l5 = lane & 31, h2 = l5 >> 3, half = lane >> 5;

    float acc0 = 0.f, acc1 = 0.f, acc2 = 0.f, acc3 = 0.f;
    float dn0 = 0.f, dn1 = 0.f, dn2 = 0.f, dn3 = 0.f;

    for (int cb = b; cb < e; cb += 64) {
        int cnt = min(64, e - cb);
        int s = 0;
        float w0 = 0.f, w1 = 0.f, w2 = 0.f, w3 = 0.f;
        if (lane < cnt) {
            s = csr[cb + lane];
            float4 av = *(const float4*)(al + (size_t)s * 16);
            float a0 = av.x + adv.x; a0 = a0 > 0.f ? a0 : 0.2f * a0; w0 = __expf(a0);
            float a1 = av.y + adv.y; a1 = a1 > 0.f ? a1 : 0.2f * a1; w1 = __expf(a1);
            float a2 = av.z + adv.z; a2 = a2 > 0.f ? a2 : 0.2f * a2; w2 = __expf(a2);
            float a3 = av.w + adv.w; a3 = a3 > 0.f ? a3 : 0.2f * a3; w3 = __expf(a3);
        }
        dn0 += w0; dn1 += w1; dn2 += w2; dn3 += w3;
        sbuf[wv][lane] = s;
        float4 wq; wq.x = w0; wq.y = w1; wq.z = w2; wq.w = w3;
        *(float4*)&wbuf[wv][lane][0] = wq;
        #pragma unroll 4
        for (int j = 0; j < cnt; j += 2) {
            int jj = j + half;              // half 1 may read j==cnt (odd tail): w=0 there
            int sj = sbuf[wv][jj];
            float wj = wbuf[wv][jj][h2];
            u32 pk = xbv[(size_t)sj * 32 + l5];
            f32x2 c01 = __builtin_amdgcn_cvt_pk_f32_fp8(pk, false);
            f32x2 c23 = __builtin_amdgcn_cvt_pk_f32_fp8(pk, true);
            acc0 = fmaf(wj, c01.x, acc0);
            acc1 = fmaf(wj, c01.y, acc1);
            acc2 = fmaf(wj, c23.x, acc2);
            acc3 = fmaf(wj, c23.y, acc3);
        }
    }
    acc0 += __shfl_xor(acc0, 32);
    acc1 += __shfl_xor(acc1, 32);
    acc2 += __shfl_xor(acc2, 32);
    acc3 += __shfl_xor(acc3, 32);
    #pragma unroll
    for (int o = 32; o > 0; o >>= 1) {
        dn0 += __shfl_xor(dn0, o);
        dn1 += __shfl_xor(dn1, o);
        dn2 += __shfl_xor(dn2, o);
        dn3 += __shfl_xor(dn3, o);
    }
    float dh = (h2 == 0) ? dn0 : (h2 == 1) ? dn1 : (h2 == 2) ? dn2 : dn3;
    float inv = 1.f / (dh + 1e-16f);
    float r0 = acc0 * inv, r1 = acc1 * inv, r2 = acc2 * inv, r3 = acc3 * inv;
    r0 = r0 > 0.f ? r0 : __expf(r0) - 1.f;
    r1 = r1 > 0.f ? r1 : __expf(r1) - 1.f;
    r2 = r2 > 0.f ? r2 : __expf(r2) - 1.f;
    r3 = r3 > 0.f ? r3 : __expf(r3) - 1.f;
    if (half == 0) {
        uint2 st;
        st.x = (u32)f2bf(r0) | ((u32)f2bf(r1) << 16);
        st.y = (u32)f2bf(r2) | ((u32)f2bf(r3) << 16);
        *(uint2*)(out + (size_t)wid * 256 + 4 * l5) = st;
    }
}

// ---------------- layer-2 propagate ----------------
__global__ __launch_bounds__(256) void k_prop2(const int* __restrict__ ptr, const u16* __restrict__ csr,
                                               const float* __restrict__ al, int didx,
                                               const uint2* __restrict__ xbv,
                                               float* __restrict__ out, int n) {
    __shared__ int2 swb[4][64];
    int tid = threadIdx.x;
    int wv = tid >> 6, lane = tid & 63;
    int wid = (blockIdx.x * 256 + tid) >> 6;
    if (wid >= n) return;
    int b = ptr[wid], e = ptr[wid + 1];
    float ad = al[(size_t)wid * 4 + didx];
    int g = lane / 10;
    int cp = lane - g * 10;
    bool act = g < 6;

    float acc0 = 0.f, acc1 = 0.f, acc2 = 0.f, acc3 = 0.f;
    float den = 0.f;

    for (int cb = b; cb < e; cb += 64) {
        int cnt = min(64, e - cb);
        int s = 0; float w = 0.f;
        if (lane < cnt) {
            s = csr[cb + lane];
            float a = al[(size_t)s * 4] + ad;
            a = a > 0.f ? a : 0.2f * a;
            w = __expf(a);
        }
        den += w;
        swb[wv][lane] = make_int2(s, __float_as_int(w));
        #pragma unroll 2
        for (int j = 0; j < cnt; j += 6) {
            int jj = j + g;
            bool valid = act && (jj < cnt);
            int2 sw = swb[wv][valid ? jj : 0];
            float wj = valid ? __int_as_float(sw.y) : 0.f;
            uint2 pk = xbv[(size_t)sw.x * 10 + cp];
            acc0 = fmaf(wj, bl(pk.x), acc0);
            acc1 = fmaf(wj, bh(pk.x), acc1);
            acc2 = fmaf(wj, bl(pk.y), acc2);
            acc3 = fmaf(wj, bh(pk.y), acc3);
        }
    }
    float t0;
    t0 = acc0 + __shfl(acc0, (lane + 30) & 63); acc0 = t0 + __shfl(t0, (lane + 10) & 63) + __shfl(t0, (lane + 20) & 63);
    t0 = acc1 + __shfl(acc1, (lane + 30) & 63); acc1 = t0 + __shfl(t0, (lane + 10) & 63) + __shfl(t0, (lane + 20) & 63);
    t0 = acc2 + __shfl(acc2, (lane + 30) & 63); acc2 = t0 + __shfl(t0, (lane + 10) & 63) + __shfl(t0, (lane + 20) & 63);
    t0 = acc3 + __shfl(acc3, (lane + 30) & 63); acc3 = t0 + __shfl(t0, (lane + 10) & 63) + __shfl(t0, (lane + 20) & 63);
    #pragma unroll
    for (int o = 32; o > 0; o >>= 1) den += __shfl_xor(den, o);
    if (lane < 10) {
        float inv = 1.f / (den + 1e-16f);
        float4 st; st.x = acc0 * inv; st.y = acc1 * inv; st.z = acc2 * inv; st.w = acc3 * inv;
        *(float4*)(out + (size_t)wid * 80 + 4 * cp) = st;
    }
}

// ---------------- log_softmax ----------------
__global__ __launch_bounds__(256) void k_lsm(const float* __restrict__ h2, float* __restrict__ out, int n) {
    int wid = (blockIdx.x * blockDim.x + threadIdx.x) >> 6;
    int lane = threadIdx.x & 63;
    if (wid >= n) return;
    const float* row = h2 + (size_t)wid * 80;
    float v0 = row[lane];
    float v1 = (lane < 16) ? row[64 + lane] : -INFINITY;
    float m = fmaxf(v0, v1);
    for (int o = 32; o > 0; o >>= 1) m = fmaxf(m, __shfl_xor(m, o));
    float s = __expf(v0 - m) + ((lane < 16) ? __expf(v1 - m) : 0.f);
    for (int o = 32; o > 0; o >>= 1) s += __shfl_xor(s, o);
    float ls = m + logf(s);
    out[(size_t)wid * 80 + lane] = v0 - ls;
    if (lane < 16) out[(size_t)wid * 80 + 64 + lane] = v1 - ls;
}

// ---------------- launch ----------------

extern "C" void kernel_launch(void* const* d_in, const int* in_sizes, int n_in,
                              void* d_out, int out_size, void* d_ws, size_t ws_size,
                              hipStream_t stream) {
    const float* x       = (const float*)d_in[0];
    const int*   e1      = (const int*)d_in[1];
    const int*   e2      = (const int*)d_in[2];
    const float* W_src1  = (const float*)d_in[3];
    const float* W_dst1  = (const float*)d_in[4];
    const float* W_dst21 = (const float*)d_in[5];
    const float* a_src1  = (const float*)d_in[6];
    const float* a_dst1  = (const float*)d_in[7];
    const float* a_dst21 = (const float*)d_in[8];
    const float* W_src2  = (const float*)d_in[9];
    const float* W_dst2  = (const float*)d_in[10];
    const float* W_dst22 = (const float*)d_in[11];
    const float* a_src2  = (const float*)d_in[12];
    const float* a_dst2  = (const float*)d_in[13];
    const float* a_dst22 = (const float*)d_in[14];
    float* out = (float*)d_out;

    const int FIN = 500;
    int n  = in_sizes[0] / FIN;     // 50000
    int E1 = in_sizes[1] / 2;       // 300000
    int E2 = in_sizes[2] / 2;       // ~1.7M
    const int* src1 = e1, *dst1 = e1 + E1;
    const int* src2 = e2, *dst2 = e2 + E2;
    int nb = (n + 511) >> 9;        // 98

    char* w = (char*)d_ws;
    auto alloc = [&](size_t bytes) -> char* {
        char* p = w; w += (bytes + 255) & ~(size_t)255; return p;
    };
    u8*    xb1  = (u8*)alloc((size_t)n * 128);        // layer1 feats fp8 [n][128]
    float* alb1 = (float*)alloc((size_t)n * 16 * 4);  // [als(4)|ald1(4)|ald21(4)|pad]
    u16*   hbuf = (u16*)alloc((size_t)n * 256 * 2);   // elu(concat) hidden bf16 [n][256]
    u16*   xb2  = (u16*)alloc((size_t)n * 40 * 2);    // layer2 feats bf16 [n][40]
    float* alb2 = (float*)alloc((size_t)n * 4 * 4);   // [als|ald1|ald22|pad]
    float* h2   = (float*)alloc((size_t)n * 80 * 4);  // pre-logsoftmax fp32
    u16*   Bt1  = (u16*)alloc(144 * 512 * 2);
    u16*   Bt2  = (u16*)alloc(48 * 256 * 2);
    int* ptr1 = (int*)alloc((size_t)(n + 1) * 4);
    u16* csr1 = (u16*)alloc((size_t)E1 * 2);
    int* ptr2 = (int*)alloc((size_t)(n + 1) * 4);
    u16* csr2 = (u16*)alloc((size_t)E2 * 2);
    int* bcnt1  = (int*)alloc(NB * 4);
    int* bcnt2  = (int*)alloc(NB * 4);
    int* bbase1 = (int*)alloc((NB + 1) * 4);
    int* bbase2 = (int*)alloc((NB + 1) * 4);
    int* bcur1  = (int*)alloc(NB * 4);
    int* bcur2  = (int*)alloc(NB * 4);
    // partition scratch aliases h2 (dead until k_prop2; stream-ordered)
    u32* part2 = (u32*)h2;
    u32* part1 = part2 + E2;

    // CSR build (bucket-first)
    hipMemsetAsync(bcnt1, 0, NB * 4, stream);
    hipMemsetAsync(bcnt2, 0, NB * 4, stream);
    k_bhist<<<(E1 + 2047) / 2048, 256, 0, stream>>>(dst1, E1, bcnt1);
    k_bhist<<<(E2 + 2047) / 2048, 256, 0, stream>>>(dst2, E2, bcnt2);
    k_bscan<<<1, NB, 0, stream>>>(bcnt1, bbase1, bcur1, ptr1 + n, nb);
    k_bscan<<<1, NB, 0, stream>>>(bcnt2, bbase2, bcur2, ptr2 + n, nb);
    k_part<<<(E1 + 2047) / 2048, 256, 0, stream>>>(src1, dst1, E1, bcur1, part1);
    k_part<<<(E2 + 2047) / 2048, 256, 0, stream>>>(src2, dst2, E2, bcur2, part2);
    k_dhs<<<nb, 256, 0, stream>>>(part1, bbase1, ptr1, csr1, n);
    k_dhs<<<nb, 256, 0, stream>>>(part2, bbase2, ptr2, csr2, n);

    // layer 1: fused MFMA GEMM (features fp8 + attention-logit projections fp32)
    k_build_Bt1<<<(144 * 512 + 255) / 256, 256, 0, stream>>>(W_src1, W_dst1, W_dst21,
                                                             a_src1, a_dst1, a_dst21, Bt1);
    k_mgemm1<<<(n + 63) / 64, 256, 0, stream>>>(x, Bt1, xb1, alb1, n);

    // layer 1 propagate (+ fused ELU), bf16 hidden out
    int pblocks = (n + 3) / 4;
    k_prop1<<<pblocks, 256, 0, stream>>>(ptr1, csr1, alb1, 4, (const u32*)xb1, hbuf + 0, n);
    k_prop1<<<pblocks, 256, 0, stream>>>(ptr2, csr2, alb1, 8, (const u32*)xb1, hbuf + 128, n);

    // layer 2: MFMA GEMM on bf16 hidden
    k_build_Bt2<<<(48 * 256 + 255) / 256, 256, 0, stream>>>(W_src2, W_dst2, W_dst22,
                                                            a_src2, a_dst2, a_dst22, Bt2);
    k_mgemm2<<<(n + 63) / 64, 256, 0, stream>>>(hbuf, Bt2, xb2, alb2, n);

    // layer 2 propagate
    k_prop2<<<pblocks, 256, 0, stream>>>(ptr1, csr1, alb2, 1, (const uint2*)xb2, h2 + 0, n);
    k_prop2<<<pblocks, 256, 0, stream>>>(ptr2, csr2, alb2, 2, (const uint2*)xb2, h2 + 40, n);

    // log_softmax
    k_lsm<<<pblocks, 256, 0, stream>>>(h2, out, n);
}